// Round 4
// baseline (1025.321 us; speedup 1.0000x reference)
//
#include <hip/hip_runtime.h>
#include <hip/hip_bf16.h>

using bf16 = __hip_bfloat16;
typedef __bf16 bf16x8_t __attribute__((ext_vector_type(8)));
typedef float f32x16_t __attribute__((ext_vector_type(16)));

#define SBAR() __builtin_amdgcn_s_barrier()
#define WAITV6() asm volatile("s_waitcnt vmcnt(6)" ::: "memory")
#define PRIO1() __builtin_amdgcn_s_setprio(1)
#define PRIO0() __builtin_amdgcn_s_setprio(0)

__device__ __forceinline__ void gload_lds16(const bf16* g, const bf16* l) {
  __builtin_amdgcn_global_load_lds(
      (const __attribute__((address_space(1))) void*)g,
      (__attribute__((address_space(3))) void*)l, 16, 0, 0);
}

// exact-GELU via A&S 7.1.26 erf (|err| < 1.5e-7)
__device__ __forceinline__ float gelu_erf(float t) {
  const float ax = fabsf(t) * 0.70710678118654752f;
  const float u = 1.0f / fmaf(0.3275911f, ax, 1.0f);
  float p = fmaf(1.061405429f, u, -1.453152027f);
  p = fmaf(p, u, 1.421413741f);
  p = fmaf(p, u, -0.284496736f);
  p = fmaf(p, u, 0.254829592f);
  p = p * u * __expf(-ax * ax);
  float er = 1.0f - p;
  er = (t < 0.f) ? -er : er;
  return 0.5f * t * (1.0f + er);
}

// LDS: [buf][mat][khalf][row 0..255][slot 0..3 of 16B]; LDS(row,slot) holds
// global 16B-slot (slot ^ ((row>>1)&3)) of that row (elements).
#define LOFF(buf, mat, kk) ((buf)*32768 + (mat)*16384 + (kk)*8192)

// ---------------- NT GEMM: C[m][n] = sum_k A[m][k] * B[n][k] ----------------
// 256x256 tile, BK=64, 8 waves, 8-phase depth-3 vmcnt(6), 32x32x16 MFMA.
template <int EPI>
__device__ __forceinline__ void gemm_body(
    const bf16* __restrict__ A, const bf16* __restrict__ B,
    void* __restrict__ Cv, int K, int lda, int ldb, int ldc,
    long long sA, long long sB, long long sC, float scale,
    const float* __restrict__ bias,
    const float* __restrict__ resid, long long sR, int ldr) {
  __shared__ __align__(16) bf16 smem[65536];  // 128 KiB
  const int tid = threadIdx.x;
  const int lane = tid & 63, wid = tid >> 6;
  const int wr = wid >> 2, wc = wid & 3;      // 2x4 waves, wave tile 128x64
  const int z = blockIdx.z;
  A += (size_t)z * sA;
  B += (size_t)z * sB;

  // T1: bijective XCD-aware block swizzle
  const int gx = gridDim.x, gy = gridDim.y;
  const int nwg = gx * gy;
  const int orig = blockIdx.x + gx * blockIdx.y;
  const int q = nwg >> 3, r = nwg & 7;
  const int xcd = orig & 7, loc = orig >> 3;
  const int wg = (xcd < r ? xcd * (q + 1) : r * (q + 1) + (xcd - r) * q) + loc;
  const int bm = (wg / gx) * 256;
  const int bn = (wg % gx) * 256;

  // staging (global src pre-swizzled, LDS dest linear)
  const int srow = tid >> 2;
  const int sgsl = (tid & 3) ^ ((srow >> 1) & 3);
  const bf16* gA0 = A + (size_t)(bm + srow) * lda + sgsl * 8;
  const bf16* gB0 = B + (size_t)(bn + srow) * ldb + sgsl * 8;

#define STAGE_A(buf, kk, ke)                                   \
  {                                                            \
    const bf16* s_ = gA0 + (ke) + (kk) * 32;                   \
    const bf16* d_ = smem + LOFF(buf, 0, kk) + wid * 512;      \
    gload_lds16(s_, d_);                                       \
    gload_lds16(s_ + (size_t)128 * lda, d_ + 4096);            \
  }
#define STAGE_B(buf, kk, ke)                                   \
  {                                                            \
    const bf16* s_ = gB0 + (ke) + (kk) * 32;                   \
    const bf16* d_ = smem + LOFF(buf, 1, kk) + wid * 512;      \
    gload_lds16(s_, d_);                                       \
    gload_lds16(s_ + (size_t)128 * ldb, d_ + 4096);            \
  }

  // fragment reads: A row = wr*128+(lane&31)+mf*32, k = ks*16+(lane>>5)*8+j
  const int l31 = lane & 31, kg = lane >> 5;
  const int sw = (l31 >> 1) & 3;
  const int rA = wr * 128 + l31;
  const int rB = wc * 64 + l31;
  const int eA0 = rA * 32 + ((kg ^ sw) * 8);            // ks=0
  const int eA1 = rA * 32 + (((2 + kg) ^ sw) * 8);      // ks=1
  const int eB0 = rB * 32 + ((kg ^ sw) * 8);
  const int eB1 = rB * 32 + (((2 + kg) ^ sw) * 8);

  f32x16_t acc[4][2] = {};
  bf16x8_t av[4], bv[2][2];

#define LOADA32(buf, kh, KS)                                        \
  {                                                                 \
    const bf16* pA_ = smem + LOFF(buf, 0, kh) + ((KS) ? eA1 : eA0); \
    _Pragma("unroll") for (int m_ = 0; m_ < 4; ++m_)                \
        av[m_] = *(const bf16x8_t*)(pA_ + m_ * 1024);               \
  }
#define LOADB32(buf, kh)                                            \
  {                                                                 \
    const bf16* p0_ = smem + LOFF(buf, 1, kh);                      \
    bv[0][0] = *(const bf16x8_t*)(p0_ + eB0);                       \
    bv[0][1] = *(const bf16x8_t*)(p0_ + eB1);                       \
    bv[1][0] = *(const bf16x8_t*)(p0_ + eB0 + 1024);                \
    bv[1][1] = *(const bf16x8_t*)(p0_ + eB1 + 1024);                \
  }
#define MM32(KS)                                                    \
  PRIO1();                                                          \
  _Pragma("unroll") for (int m_ = 0; m_ < 4; ++m_)                  \
      _Pragma("unroll") for (int n_ = 0; n_ < 2; ++n_)              \
          acc[m_][n_] = __builtin_amdgcn_mfma_f32_32x32x16_bf16(    \
              av[m_], bv[n_][KS], acc[m_][n_], 0, 0, 0);            \
  PRIO0();

  const int nt = K >> 6;
  const int km = nt - 1;
  const int nit = nt >> 1;

  // prologue: t0 full + t1.{B.k0, A.k0, B.k1}; vmcnt(6) -> t0 resident.
  STAGE_A(0, 0, 0); STAGE_B(0, 0, 0);
  STAGE_A(0, 1, 0); STAGE_B(0, 1, 0);
  STAGE_B(1, 0, 64); STAGE_A(1, 0, 64); STAGE_B(1, 1, 64);
  WAITV6();
  SBAR();

  for (int i = 0; i < nit; ++i) {
    const int ke1 = (2 * i + 1) * 64;
    const int ke2 = ((2 * i + 2) & km) * 64;
    const int ke3 = ((2 * i + 3) & km) * 64;
    // p1
    LOADA32(0, 0, 0); LOADB32(0, 0);
    STAGE_A(1, 1, ke1);
    SBAR(); MM32(0); SBAR();
    // p2
    LOADA32(0, 0, 1);
    STAGE_B(0, 0, ke2);
    SBAR(); MM32(1); SBAR();
    // p3
    LOADA32(0, 1, 0); LOADB32(0, 1);
    STAGE_A(0, 0, ke2);
    SBAR(); MM32(0); SBAR();
    // p4
    LOADA32(0, 1, 1);
    STAGE_B(0, 1, ke2);
    SBAR(); MM32(1);
    WAITV6(); SBAR();
    // p5
    LOADA32(1, 0, 0); LOADB32(1, 0);
    STAGE_A(0, 1, ke2);
    SBAR(); MM32(0); SBAR();
    // p6
    LOADA32(1, 0, 1);
    STAGE_B(1, 0, ke3);
    SBAR(); MM32(1); SBAR();
    // p7
    LOADA32(1, 1, 0); LOADB32(1, 1);
    STAGE_A(1, 0, ke3);
    SBAR(); MM32(0); SBAR();
    // p8
    LOADA32(1, 1, 1);
    STAGE_B(1, 1, ke3);
    SBAR(); MM32(1);
    WAITV6(); SBAR();
  }
  asm volatile("s_waitcnt vmcnt(0) lgkmcnt(0)" ::: "memory");
  SBAR();

  // ---- epilogue (32x32 C/D layout: col=lane&31, row=(reg&3)+8(reg>>2)+4kg) --
  const int row0 = bm + wr * 128;
  const int col0 = bn + wc * 64 + l31;
#pragma unroll
  for (int mf = 0; mf < 4; ++mf) {
#pragma unroll
    for (int nf = 0; nf < 2; ++nf) {
#pragma unroll
      for (int reg = 0; reg < 16; ++reg) {
        const int rr = row0 + mf * 32 + (reg & 3) + 8 * (reg >> 2) + 4 * kg;
        const int cc = col0 + nf * 32;
        const float v = acc[mf][nf][reg];
        if constexpr (EPI == 0) {
          ((bf16*)Cv)[(size_t)z * sC + (size_t)rr * ldc + cc] = __float2bfloat16(v);
        } else if constexpr (EPI == 1) {
          ((float*)Cv)[(size_t)z * sC + (size_t)rr * ldc + cc] = v * scale;
        } else if constexpr (EPI == 2) {
          ((float*)Cv)[(size_t)z * sC + (size_t)rr * ldc + cc] =
              v + resid[(size_t)z * sR + (size_t)rr * ldr + cc];
        } else if constexpr (EPI == 3) {
          ((bf16*)Cv)[(size_t)z * sC + (size_t)rr * ldc + cc] =
              __float2bfloat16(gelu_erf(v + bias[cc]));
        } else {
          float* Cf = (float*)Cv + (size_t)z * sC;
          const size_t idx = (size_t)rr * ldc + cc;
          Cf[idx] = Cf[idx] + v + bias[cc];
        }
      }
    }
  }
#undef STAGE_A
#undef STAGE_B
#undef LOADA32
#undef LOADB32
#undef MM32
}

// Named wrappers (rocprof attribution)
__launch_bounds__(512, 2) __global__ void gemm_qkv(
    const bf16* A, const bf16* B, void* C, int K, int lda, int ldb, int ldc,
    long long sA, long long sB, long long sC) {
  gemm_body<0>(A, B, C, K, lda, ldb, ldc, sA, sB, sC, 1.f, nullptr, nullptr, 0, 0);
}
__launch_bounds__(512, 2) __global__ void gemm_qkt(
    const bf16* A, const bf16* B, void* C, int K, int lda, int ldb, int ldc,
    long long sA, long long sB, long long sC, float scale) {
  gemm_body<1>(A, B, C, K, lda, ldb, ldc, sA, sB, sC, scale, nullptr, nullptr, 0, 0);
}
__launch_bounds__(512, 2) __global__ void gemm_pv(
    const bf16* A, const bf16* B, void* C, int K, int lda, int ldb, int ldc,
    long long sA, long long sB, long long sC, const float* resid, long long sR,
    int ldr) {
  gemm_body<2>(A, B, C, K, lda, ldb, ldc, sA, sB, sC, 1.f, nullptr, resid, sR, ldr);
}
__launch_bounds__(512, 2) __global__ void gemm_ffn1(
    const bf16* A, const bf16* B, void* C, int K, int lda, int ldb, int ldc,
    const float* bias) {
  gemm_body<3>(A, B, C, K, lda, ldb, ldc, 0, 0, 0, 1.f, bias, nullptr, 0, 0);
}
__launch_bounds__(512, 2) __global__ void gemm_ffn2(
    const bf16* A, const bf16* B, void* C, int K, int lda, int ldb, int ldc,
    const float* bias) {
  gemm_body<4>(A, B, C, K, lda, ldb, ldc, 0, 0, 0, 1.f, bias, nullptr, 0, 0);
}

// ---------------- LayerNorm: fp32 in -> bf16 out, row length 1024 ----------
__global__ void ln_kernel(const float* __restrict__ X, const float* __restrict__ gw,
                          const float* __restrict__ bw, bf16* __restrict__ Y) {
  const int row = blockIdx.x, tid = threadIdx.x;
  const float4 xv = *(const float4*)(X + (size_t)row * 1024 + tid * 4);
  float s = xv.x + xv.y + xv.z + xv.w;
  float ss = xv.x * xv.x + xv.y * xv.y + xv.z * xv.z + xv.w * xv.w;
  __shared__ float red[8];
#pragma unroll
  for (int o = 32; o; o >>= 1) {
    s += __shfl_xor(s, o);
    ss += __shfl_xor(ss, o);
  }
  if ((tid & 63) == 0) {
    red[tid >> 6] = s;
    red[4 + (tid >> 6)] = ss;
  }
  __syncthreads();
  s = red[0] + red[1] + red[2] + red[3];
  ss = red[4] + red[5] + red[6] + red[7];
  const float mu = s * (1.f / 1024.f);
  const float var = ss * (1.f / 1024.f) - mu * mu;
  const float rs = rsqrtf(var + 1e-5f);
  const float4 gv = *(const float4*)(gw + tid * 4);
  const float4 bv = *(const float4*)(bw + tid * 4);
  union { ushort4 u; bf16 h[4]; } p;
  p.h[0] = __float2bfloat16((xv.x - mu) * rs * gv.x + bv.x);
  p.h[1] = __float2bfloat16((xv.y - mu) * rs * gv.y + bv.y);
  p.h[2] = __float2bfloat16((xv.z - mu) * rs * gv.z + bv.z);
  p.h[3] = __float2bfloat16((xv.w - mu) * rs * gv.w + bv.w);
  *(ushort4*)(Y + (size_t)row * 1024 + tid * 4) = p.u;
}

// ---------------- Softmax over rows of 2048 fp32 -> bf16 -------------------
__global__ void softmax_kernel(const float* __restrict__ S, bf16* __restrict__ P) {
  const size_t row = blockIdx.x;
  const int tid = threadIdx.x;
  const float4* sp = (const float4*)(S + row * 2048);
  const float4 v0 = sp[tid * 2], v1 = sp[tid * 2 + 1];
  float f[8] = {v0.x, v0.y, v0.z, v0.w, v1.x, v1.y, v1.z, v1.w};
  float m = f[0];
#pragma unroll
  for (int j = 1; j < 8; ++j) m = fmaxf(m, f[j]);
  __shared__ float red[4];
#pragma unroll
  for (int o = 32; o; o >>= 1) m = fmaxf(m, __shfl_xor(m, o));
  if ((tid & 63) == 0) red[tid >> 6] = m;
  __syncthreads();
  m = fmaxf(fmaxf(red[0], red[1]), fmaxf(red[2], red[3]));
  float s = 0.f;
#pragma unroll
  for (int j = 0; j < 8; ++j) {
    f[j] = expf(f[j] - m);
    s += f[j];
  }
#pragma unroll
  for (int o = 32; o; o >>= 1) s += __shfl_xor(s, o);
  __syncthreads();
  if ((tid & 63) == 0) red[tid >> 6] = s;
  __syncthreads();
  s = red[0] + red[1] + red[2] + red[3];
  const float inv = 1.f / s;
  union { uint4 u; bf16 h[8]; } p;
#pragma unroll
  for (int j = 0; j < 8; ++j) p.h[j] = __float2bfloat16(f[j] * inv);
  *(uint4*)(P + row * 2048 + tid * 8) = p.u;
}

// ------- Transpose + convert fp32 W[K][N] -> bf16 WT[rowoff+n][k] ----------
__global__ void transpose_conv(const float* __restrict__ W, bf16* __restrict__ WT,
                               int Nd, int ldT, int rowoff) {
  __shared__ float t[32][33];
  const int tx = threadIdx.x, ty = threadIdx.y;
  const int n0 = blockIdx.x * 32, k0 = blockIdx.y * 32;
#pragma unroll
  for (int j = 0; j < 4; ++j)
    t[ty + 8 * j][tx] = W[(size_t)(k0 + ty + 8 * j) * Nd + n0 + tx];
  __syncthreads();
#pragma unroll
  for (int j = 0; j < 4; ++j)
    WT[(size_t)(rowoff + n0 + ty + 8 * j) * ldT + k0 + tx] =
        __float2bfloat16(t[tx][ty + 8 * j]);
}

// ------- bf16 transpose: dst[c][r] = src[r][c], batched over z -------------
__global__ void transpose_bf16(const bf16* __restrict__ src, bf16* __restrict__ dst,
                               int ldsrc, int lddst, long long zs, long long zd) {
  __shared__ bf16 t[32][33];
  const int z = blockIdx.z;
  src += (size_t)z * zs;
  dst += (size_t)z * zd;
  const int tx = threadIdx.x, ty = threadIdx.y;
  const int c0 = blockIdx.x * 32, r0 = blockIdx.y * 32;
#pragma unroll
  for (int j = 0; j < 4; ++j)
    t[ty + 8 * j][tx] = src[(size_t)(r0 + ty + 8 * j) * ldsrc + c0 + tx];
  __syncthreads();
#pragma unroll
  for (int j = 0; j < 4; ++j)
    dst[(size_t)(c0 + ty + 8 * j) * lddst + r0 + tx] = t[tx][ty + 8 * j];
}

extern "C" void kernel_launch(void* const* d_in, const int* in_sizes, int n_in,
                              void* d_out, int out_size, void* d_ws, size_t ws_size,
                              hipStream_t stream) {
  const float* x = (const float*)d_in[0];
  const float* ln1_g = (const float*)d_in[1];
  const float* ln1_b = (const float*)d_in[2];
  const float* Wq = (const float*)d_in[3];
  const float* Wk = (const float*)d_in[4];
  const float* Wv = (const float*)d_in[5];
  const float* ln2_g = (const float*)d_in[6];
  const float* ln2_b = (const float*)d_in[7];
  const float* W1 = (const float*)d_in[8];
  const float* b1 = (const float*)d_in[9];
  const float* W2 = (const float*)d_in[10];
  const float* b2 = (const float*)d_in[11];
  float* out = (float*)d_out;

  constexpr int B = 8, N = 2048, H = 1024, F = 4096;
  constexpr int M = B * N;  // 16384

  const size_t WqkvTB = (size_t)3 * H * H * 2;
  const size_t W1TB = (size_t)H * F * 2;
  const size_t W2TB = (size_t)H * F * 2;
  const size_t yB = (size_t)M * H * 2;
  const size_t vTB = (size_t)M * H * 2;
  const size_t qkvB = (size_t)M * 3 * H * 2;
  const size_t SB1 = (size_t)N * N * 4;
  const size_t attB1 = (size_t)N * N * 2;
  const size_t hB = (size_t)M * F * 2;
  const size_t fixedB = WqkvTB + W1TB + W2TB + yB + vTB;

  int g = 8;
  for (; g > 1; g >>= 1) {
    size_t R = qkvB + (size_t)g * (SB1 + attB1);
    if (R < hB) R = hB;
    if (fixedB + R <= ws_size) break;
  }

  char* ws = (char*)d_ws;
  size_t o = 0;
  bf16* wqkvT = (bf16*)(ws + o); o += WqkvTB;
  bf16* w1T = (bf16*)(ws + o);   o += W1TB;
  bf16* w2T = (bf16*)(ws + o);   o += W2TB;
  bf16* y = (bf16*)(ws + o);     o += yB;
  bf16* vT = (bf16*)(ws + o);    o += vTB;
  char* Rb = ws + o;
  bf16* qkv = (bf16*)Rb;
  float* S = (float*)(Rb + qkvB);
  bf16* att = (bf16*)(Rb + qkvB + (size_t)g * SB1);
  bf16* h = (bf16*)Rb;

  const dim3 tb(32, 8);
  transpose_conv<<<dim3(H / 32, H / 32), tb, 0, stream>>>(Wq, wqkvT, H, H, 0);
  transpose_conv<<<dim3(H / 32, H / 32), tb, 0, stream>>>(Wk, wqkvT, H, H, H);
  transpose_conv<<<dim3(H / 32, H / 32), tb, 0, stream>>>(Wv, wqkvT, H, H, 2 * H);
  transpose_conv<<<dim3(F / 32, H / 32), tb, 0, stream>>>(W1, w1T, F, H, 0);
  transpose_conv<<<dim3(H / 32, F / 32), tb, 0, stream>>>(W2, w2T, H, F, 0);

  ln_kernel<<<M, 256, 0, stream>>>(x, ln1_g, ln1_b, y);

  gemm_qkv<<<dim3(3 * H / 256, M / 256, 1), 512, 0, stream>>>(
      y, wqkvT, qkv, H, H, H, 3 * H, 0, 0, 0);

  transpose_bf16<<<dim3(H / 32, N / 32, B), tb, 0, stream>>>(
      qkv + 2 * H, vT, 3 * H, N, (long long)N * 3 * H, (long long)H * N);

  for (int b0 = 0; b0 < B; b0 += g) {
    const bf16* qb = qkv + (size_t)b0 * N * 3 * H;
    gemm_qkt<<<dim3(N / 256, N / 256, g), 512, 0, stream>>>(
        qb, qb + H, S, H, 3 * H, 3 * H, N, (long long)N * 3 * H,
        (long long)N * 3 * H, (long long)N * N, 0.03125f);
    softmax_kernel<<<g * N, 256, 0, stream>>>(S, att);
    gemm_pv<<<dim3(H / 256, N / 256, g), 512, 0, stream>>>(
        att, vT + (size_t)b0 * H * N, out + (size_t)b0 * N * H, N, N, N, H,
        (long long)N * N, (long long)H * N, (long long)N * H,
        x + (size_t)b0 * N * H, (long long)N * H, H);
  }

  ln_kernel<<<M, 256, 0, stream>>>(out, ln2_g, ln2_b, y);

  gemm_ffn1<<<dim3(F / 256, M / 256, 1), 512, 0, stream>>>(
      y, w1T, h, H, H, H, F, b1);

  gemm_ffn2<<<dim3(H / 256, M / 256, 1), 512, 0, stream>>>(
      h, w2T, out, F, F, F, H, b2);
}

// Round 6
// 999.765 us; speedup vs baseline: 1.0256x; 1.0256x over previous
//
#include <hip/hip_runtime.h>
#include <hip/hip_bf16.h>

using bf16 = __hip_bfloat16;
typedef __bf16 bf16x8_t __attribute__((ext_vector_type(8)));
typedef float f32x4_t __attribute__((ext_vector_type(4)));

#define SBAR() __builtin_amdgcn_s_barrier()
#define WAITV4() asm volatile("s_waitcnt vmcnt(4)" ::: "memory")
#define WAITLG() asm volatile("s_waitcnt lgkmcnt(0)" ::: "memory")
#define PRIO1() __builtin_amdgcn_s_setprio(1)
#define PRIO0() __builtin_amdgcn_s_setprio(0)

__device__ __forceinline__ void gload_lds16(const bf16* g, const bf16* l) {
  __builtin_amdgcn_global_load_lds(
      (const __attribute__((address_space(1))) void*)g,
      (__attribute__((address_space(3))) void*)l, 16, 0, 0);
}

// exact-GELU via A&S 7.1.26 erf (|err| < 1.5e-7)
__device__ __forceinline__ float gelu_erf(float t) {
  const float ax = fabsf(t) * 0.70710678118654752f;
  const float u = 1.0f / fmaf(0.3275911f, ax, 1.0f);
  float p = fmaf(1.061405429f, u, -1.453152027f);
  p = fmaf(p, u, 1.421413741f);
  p = fmaf(p, u, -0.284496736f);
  p = fmaf(p, u, 0.254829592f);
  p = p * u * __expf(-ax * ax);
  float er = 1.0f - p;
  er = (t < 0.f) ? -er : er;
  return 0.5f * t * (1.0f + er);
}

// LDS: A = [buf][half][128 rows][64 k] at 0; B same at +32768 elem.
// Swizzle: LDS(row, slot) holds global 16B-slot (slot ^ ((row>>2)&1)<<1).
// Half h of A holds global rows bm+h*128..+127 (B: bn+h*128..).
// Wave row interleave: wave wr owns rows {mh*128 + wr*64 + mf*16 + l15},
// wave wc owns cols {nh*128 + wc*32 + nf*16 + l15}.

// ---------------- NT GEMM: C[m][n] = sum_k A[m][k] * B[n][k] ----------------
// 256x256 tile, BK=64, 8 waves (2Mx4N), 4 quadrant-phases/K-tile,
// 1 half-tile staged per phase, uniform vmcnt(4) per phase-end.
template <int EPI>
__device__ __forceinline__ void gemm_body(
    const bf16* __restrict__ A, const bf16* __restrict__ B,
    void* __restrict__ Cv, int K, int lda, int ldb, int ldc,
    long long sA, long long sB, long long sC, float scale,
    const float* __restrict__ bias,
    const float* __restrict__ resid, long long sR, int ldr) {
  __shared__ __align__(16) bf16 smem[65536];  // 128 KiB
  const int tid = threadIdx.x;
  const int lane = tid & 63, wid = tid >> 6;
  const int wr = wid >> 2, wc = wid & 3;
  const int z = blockIdx.z;
  A += (size_t)z * sA;
  B += (size_t)z * sB;

  // T1: bijective XCD-aware block swizzle
  const int gx = gridDim.x, gy = gridDim.y;
  const int nwg = gx * gy;
  const int orig = blockIdx.x + gx * blockIdx.y;
  const int q = nwg >> 3, r = nwg & 7;
  const int xcd = orig & 7, loc = orig >> 3;
  const int wg = (xcd < r ? xcd * (q + 1) : r * (q + 1) + (xcd - r) * q) + loc;
  const int bm = (wg / gx) * 256;
  const int bn = (wg % gx) * 256;

  // ---- staging: thread -> (row srow & srow+64 of the half, swizzled slot)
  const int srow = tid >> 3;                            // 0..63
  const int sslot = (tid & 7) ^ (((srow >> 2) & 1) << 1);
  const bf16* gA = A + (size_t)(bm + srow) * lda + sslot * 8;
  const bf16* gB = B + (size_t)(bn + srow) * ldb + sslot * 8;
  const int sdst = wid * 512;  // wave-uniform LDS dest (HW adds lane*16B)

#define STAGE_A(SB, H, KE)                                                  \
  {                                                                         \
    const bf16* s_ = gA + (size_t)((H)*128) * lda + (KE);                   \
    gload_lds16(s_, smem + (SB)*16384 + (H)*8192 + sdst);                   \
    gload_lds16(s_ + (size_t)64 * lda,                                      \
                smem + (SB)*16384 + (H)*8192 + sdst + 4096);                \
  }
#define STAGE_B(SB, H, KE)                                                  \
  {                                                                         \
    const bf16* s_ = gB + (size_t)((H)*128) * ldb + (KE);                   \
    gload_lds16(s_, smem + 32768 + (SB)*16384 + (H)*8192 + sdst);           \
    gload_lds16(s_ + (size_t)64 * ldb,                                      \
                smem + 32768 + (SB)*16384 + (H)*8192 + sdst + 4096);        \
  }

  // ---- fragment read constants ----
  const int l15 = lane & 15, kg16 = lane >> 4;
  const int swzc = ((lane >> 2) & 1) << 1;          // row-bit2 = l15 bit2
  const int slot0 = (kg16 ^ swzc) * 8;              // ks adds +32 (bit2)
  const int rdA = wr * 4096 + l15 * 64 + slot0;     // + mh*8192 + mf*1024
  const int rdB = 32768 + wc * 2048 + l15 * 64 + slot0;  // + nh*8192 + nf*1024

  f32x4_t acc[8][4] = {};
  bf16x8_t avA[4][2], bvB[2][2];

#define LDA(BUF, MH)                                                        \
  _Pragma("unroll") for (int mf = 0; mf < 4; ++mf)                          \
      _Pragma("unroll") for (int ks = 0; ks < 2; ++ks)                      \
          avA[mf][ks] = *(const bf16x8_t*)(smem + (BUF)*16384 +             \
                                           (MH)*8192 + rdA + mf * 1024 +    \
                                           ks * 32);
#define LDB(BUF, NH)                                                        \
  _Pragma("unroll") for (int nf = 0; nf < 2; ++nf)                          \
      _Pragma("unroll") for (int ks = 0; ks < 2; ++ks)                      \
          bvB[nf][ks] = *(const bf16x8_t*)(smem + (BUF)*16384 +             \
                                           (NH)*8192 + rdB + nf * 1024 +    \
                                           ks * 32);
#define MMQ(MH, NH)                                                         \
  PRIO1();                                                                  \
  _Pragma("unroll") for (int ks = 0; ks < 2; ++ks)                          \
      _Pragma("unroll") for (int mf = 0; mf < 4; ++mf)                      \
          _Pragma("unroll") for (int nf = 0; nf < 2; ++nf)                  \
              acc[(MH)*4 + mf][(NH)*2 + nf] =                               \
                  __builtin_amdgcn_mfma_f32_16x16x32_bf16(                  \
                      avA[mf][ks], bvB[nf][ks],                             \
                      acc[(MH)*4 + mf][(NH)*2 + nf], 0, 0, 0);              \
  PRIO0();

// Quadrant snake (0,0)->(0,1)->(1,1)->(1,0); stage order A0,B0,B1,A1 of
// tile t+1 into buffer SB. FIFO ledger (2 loads/phase, vmcnt(4) each
// phase-end): every first-read is >=2 phases after its stage => resident.
#define KTILE(BUF, SB, KE)                                                  \
  LDA(BUF, 0); LDB(BUF, 0); STAGE_A(SB, 0, KE);                             \
  SBAR(); WAITLG(); MMQ(0, 0); WAITV4(); SBAR();                           \
  LDB(BUF, 1); STAGE_B(SB, 0, KE);                                         \
  SBAR(); WAITLG(); MMQ(0, 1); WAITV4(); SBAR();                           \
  LDA(BUF, 1); STAGE_B(SB, 1, KE);                                         \
  SBAR(); WAITLG(); MMQ(1, 1); WAITV4(); SBAR();                           \
  LDB(BUF, 0); STAGE_A(SB, 1, KE);                                         \
  SBAR(); WAITLG(); MMQ(1, 0); WAITV4(); SBAR();

  const int nt = K >> 6;  // 16/32/64 here (power of two)
  const int km = nt - 1;
  const int nit = nt >> 1;

  // prologue: tile0 halves in first-read order A0,B0,B1,A1; vmcnt(4)
  // -> A0,B0 resident; B1 proven at ph1-end, A1 at ph2-end.
  STAGE_A(0, 0, 0); STAGE_B(0, 0, 0); STAGE_B(0, 1, 0); STAGE_A(0, 1, 0);
  WAITV4();
  SBAR();

  for (int i = 0; i < nit; ++i) {
    const int keA = ((2 * i + 1) & km) * 64;
    const int keB = ((2 * i + 2) & km) * 64;  // wraps harmlessly on tail
    KTILE(0, 1, keA);
    KTILE(1, 0, keB);
  }
  asm volatile("s_waitcnt vmcnt(0) lgkmcnt(0)" ::: "memory");
  SBAR();

  // ---- epilogue (16x16 C/D: col=lane&15, row=(lane>>4)*4+reg) ----
#pragma unroll
  for (int mi = 0; mi < 8; ++mi) {
    const int rbase =
        bm + (mi >> 2) * 128 + wr * 64 + (mi & 3) * 16 + kg16 * 4;
#pragma unroll
    for (int ni = 0; ni < 4; ++ni) {
      const int cc = bn + (ni >> 1) * 128 + wc * 32 + (ni & 1) * 16 + l15;
#pragma unroll
      for (int jj = 0; jj < 4; ++jj) {
        const int rr = rbase + jj;
        const float v = acc[mi][ni][jj];
        if constexpr (EPI == 0) {
          ((bf16*)Cv)[(size_t)z * sC + (size_t)rr * ldc + cc] = __float2bfloat16(v);
        } else if constexpr (EPI == 1) {
          ((float*)Cv)[(size_t)z * sC + (size_t)rr * ldc + cc] = v * scale;
        } else if constexpr (EPI == 2) {
          ((float*)Cv)[(size_t)z * sC + (size_t)rr * ldc + cc] =
              v + resid[(size_t)z * sR + (size_t)rr * ldr + cc];
        } else if constexpr (EPI == 3) {
          ((bf16*)Cv)[(size_t)z * sC + (size_t)rr * ldc + cc] =
              __float2bfloat16(gelu_erf(v + bias[cc]));
        } else {
          float* Cf = (float*)Cv + (size_t)z * sC;
          const size_t idx = (size_t)rr * ldc + cc;
          Cf[idx] = Cf[idx] + v + bias[cc];
        }
      }
    }
  }
#undef STAGE_A
#undef STAGE_B
#undef LDA
#undef LDB
#undef MMQ
#undef KTILE
}

// Named wrappers (rocprof attribution)
__launch_bounds__(512, 1) __global__ void gemm_qkv(
    const bf16* A, const bf16* B, void* C, int K, int lda, int ldb, int ldc,
    long long sA, long long sB, long long sC) {
  gemm_body<0>(A, B, C, K, lda, ldb, ldc, sA, sB, sC, 1.f, nullptr, nullptr, 0, 0);
}
__launch_bounds__(512, 1) __global__ void gemm_qkt(
    const bf16* A, const bf16* B, void* C, int K, int lda, int ldb, int ldc,
    long long sA, long long sB, long long sC, float scale) {
  gemm_body<1>(A, B, C, K, lda, ldb, ldc, sA, sB, sC, scale, nullptr, nullptr, 0, 0);
}
__launch_bounds__(512, 1) __global__ void gemm_pv(
    const bf16* A, const bf16* B, void* C, int K, int lda, int ldb, int ldc,
    long long sA, long long sB, long long sC, const float* resid, long long sR,
    int ldr) {
  gemm_body<2>(A, B, C, K, lda, ldb, ldc, sA, sB, sC, 1.f, nullptr, resid, sR, ldr);
}
__launch_bounds__(512, 1) __global__ void gemm_ffn1(
    const bf16* A, const bf16* B, void* C, int K, int lda, int ldb, int ldc,
    const float* bias) {
  gemm_body<3>(A, B, C, K, lda, ldb, ldc, 0, 0, 0, 1.f, bias, nullptr, 0, 0);
}
__launch_bounds__(512, 1) __global__ void gemm_ffn2(
    const bf16* A, const bf16* B, void* C, int K, int lda, int ldb, int ldc,
    const float* bias) {
  gemm_body<4>(A, B, C, K, lda, ldb, ldc, 0, 0, 0, 1.f, bias, nullptr, 0, 0);
}

// ---------------- LayerNorm: fp32 in -> bf16 out, row length 1024 ----------
__global__ void ln_kernel(const float* __restrict__ X, const float* __restrict__ gw,
                          const float* __restrict__ bw, bf16* __restrict__ Y) {
  const int row = blockIdx.x, tid = threadIdx.x;
  const float4 xv = *(const float4*)(X + (size_t)row * 1024 + tid * 4);
  float s = xv.x + xv.y + xv.z + xv.w;
  float ss = xv.x * xv.x + xv.y * xv.y + xv.z * xv.z + xv.w * xv.w;
  __shared__ float red[8];
#pragma unroll
  for (int o = 32; o; o >>= 1) {
    s += __shfl_xor(s, o);
    ss += __shfl_xor(ss, o);
  }
  if ((tid & 63) == 0) {
    red[tid >> 6] = s;
    red[4 + (tid >> 6)] = ss;
  }
  __syncthreads();
  s = red[0] + red[1] + red[2] + red[3];
  ss = red[4] + red[5] + red[6] + red[7];
  const float mu = s * (1.f / 1024.f);
  const float var = ss * (1.f / 1024.f) - mu * mu;
  const float rs = rsqrtf(var + 1e-5f);
  const float4 gv = *(const float4*)(gw + tid * 4);
  const float4 bv = *(const float4*)(bw + tid * 4);
  union { ushort4 u; bf16 h[4]; } p;
  p.h[0] = __float2bfloat16((xv.x - mu) * rs * gv.x + bv.x);
  p.h[1] = __float2bfloat16((xv.y - mu) * rs * gv.y + bv.y);
  p.h[2] = __float2bfloat16((xv.z - mu) * rs * gv.z + bv.z);
  p.h[3] = __float2bfloat16((xv.w - mu) * rs * gv.w + bv.w);
  *(ushort4*)(Y + (size_t)row * 1024 + tid * 4) = p.u;
}

// ---------------- Softmax over rows of 2048 fp32 -> bf16 -------------------
__global__ void softmax_kernel(const float* __restrict__ S, bf16* __restrict__ P) {
  const size_t row = blockIdx.x;
  const int tid = threadIdx.x;
  const float4* sp = (const float4*)(S + row * 2048);
  const float4 v0 = sp[tid * 2], v1 = sp[tid * 2 + 1];
  float f[8] = {v0.x, v0.y, v0.z, v0.w, v1.x, v1.y, v1.z, v1.w};
  float m = f[0];
#pragma unroll
  for (int j = 1; j < 8; ++j) m = fmaxf(m, f[j]);
  __shared__ float red[4];
#pragma unroll
  for (int o = 32; o; o >>= 1) m = fmaxf(m, __shfl_xor(m, o));
  if ((tid & 63) == 0) red[tid >> 6] = m;
  __syncthreads();
  m = fmaxf(fmaxf(red[0], red[1]), fmaxf(red[2], red[3]));
  float s = 0.f;
#pragma unroll
  for (int j = 0; j < 8; ++j) {
    f[j] = expf(f[j] - m);
    s += f[j];
  }
#pragma unroll
  for (int o = 32; o; o >>= 1) s += __shfl_xor(s, o);
  __syncthreads();
  if ((tid & 63) == 0) red[tid >> 6] = s;
  __syncthreads();
  s = red[0] + red[1] + red[2] + red[3];
  const float inv = 1.f / s;
  union { uint4 u; bf16 h[8]; } p;
#pragma unroll
  for (int j = 0; j < 8; ++j) p.h[j] = __float2bfloat16(f[j] * inv);
  *(uint4*)(P + row * 2048 + tid * 8) = p.u;
}

// ------- Transpose + convert fp32 W[K][N] -> bf16 WT[rowoff+n][k] ----------
__global__ void transpose_conv(const float* __restrict__ W, bf16* __restrict__ WT,
                               int Nd, int ldT, int rowoff) {
  __shared__ float t[32][33];
  const int tx = threadIdx.x, ty = threadIdx.y;
  const int n0 = blockIdx.x * 32, k0 = blockIdx.y * 32;
#pragma unroll
  for (int j = 0; j < 4; ++j)
    t[ty + 8 * j][tx] = W[(size_t)(k0 + ty + 8 * j) * Nd + n0 + tx];
  __syncthreads();
#pragma unroll
  for (int j = 0; j < 4; ++j)
    WT[(size_t)(rowoff + n0 + ty + 8 * j) * ldT + k0 + tx] =
        __float2bfloat16(t[tx][ty + 8 * j]);
}

// ------- bf16 transpose: dst[c][r] = src[r][c], batched over z -------------
__global__ void transpose_bf16(const bf16* __restrict__ src, bf16* __restrict__ dst,
                               int ldsrc, int lddst, long long zs, long long zd) {
  __shared__ bf16 t[32][33];
  const int z = blockIdx.z;
  src += (size_t)z * zs;
  dst += (size_t)z * zd;
  const int tx = threadIdx.x, ty = threadIdx.y;
  const int c0 = blockIdx.x * 32, r0 = blockIdx.y * 32;
#pragma unroll
  for (int j = 0; j < 4; ++j)
    t[ty + 8 * j][tx] = src[(size_t)(r0 + ty + 8 * j) * ldsrc + c0 + tx];
  __syncthreads();
#pragma unroll
  for (int j = 0; j < 4; ++j)
    dst[(size_t)(c0 + ty + 8 * j) * lddst + r0 + tx] = t[tx][ty + 8 * j];
}

extern "C" void kernel_launch(void* const* d_in, const int* in_sizes, int n_in,
                              void* d_out, int out_size, void* d_ws, size_t ws_size,
                              hipStream_t stream) {
  const float* x = (const float*)d_in[0];
  const float* ln1_g = (const float*)d_in[1];
  const float* ln1_b = (const float*)d_in[2];
  const float* Wq = (const float*)d_in[3];
  const float* Wk = (const float*)d_in[4];
  const float* Wv = (const float*)d_in[5];
  const float* ln2_g = (const float*)d_in[6];
  const float* ln2_b = (const float*)d_in[7];
  const float* W1 = (const float*)d_in[8];
  const float* b1 = (const float*)d_in[9];
  const float* W2 = (const float*)d_in[10];
  const float* b2 = (const float*)d_in[11];
  float* out = (float*)d_out;

  constexpr int B = 8, N = 2048, H = 1024, F = 4096;
  constexpr int M = B * N;  // 16384

  const size_t WqkvTB = (size_t)3 * H * H * 2;
  const size_t W1TB = (size_t)H * F * 2;
  const size_t W2TB = (size_t)H * F * 2;
  const size_t yB = (size_t)M * H * 2;
  const size_t vTB = (size_t)M * H * 2;
  const size_t qkvB = (size_t)M * 3 * H * 2;
  const size_t SB1 = (size_t)N * N * 4;
  const size_t attB1 = (size_t)N * N * 2;
  const size_t hB = (size_t)M * F * 2;
  const size_t fixedB = WqkvTB + W1TB + W2TB + yB + vTB;

  int g = 8;
  for (; g > 1; g >>= 1) {
    size_t R = qkvB + (size_t)g * (SB1 + attB1);
    if (R < hB) R = hB;
    if (fixedB + R <= ws_size) break;
  }

  char* ws = (char*)d_ws;
  size_t o = 0;
  bf16* wqkvT = (bf16*)(ws + o); o += WqkvTB;
  bf16* w1T = (bf16*)(ws + o);   o += W1TB;
  bf16* w2T = (bf16*)(ws + o);   o += W2TB;
  bf16* y = (bf16*)(ws + o);     o += yB;
  bf16* vT = (bf16*)(ws + o);    o += vTB;
  char* Rb = ws + o;
  bf16* qkv = (bf16*)Rb;
  float* S = (float*)(Rb + qkvB);
  bf16* att = (bf16*)(Rb + qkvB + (size_t)g * SB1);
  bf16* h = (bf16*)Rb;

  const dim3 tb(32, 8);
  transpose_conv<<<dim3(H / 32, H / 32), tb, 0, stream>>>(Wq, wqkvT, H, H, 0);
  transpose_conv<<<dim3(H / 32, H / 32), tb, 0, stream>>>(Wk, wqkvT, H, H, H);
  transpose_conv<<<dim3(H / 32, H / 32), tb, 0, stream>>>(Wv, wqkvT, H, H, 2 * H);
  transpose_conv<<<dim3(F / 32, H / 32), tb, 0, stream>>>(W1, w1T, F, H, 0);
  transpose_conv<<<dim3(H / 32, F / 32), tb, 0, stream>>>(W2, w2T, H, F, 0);

  ln_kernel<<<M, 256, 0, stream>>>(x, ln1_g, ln1_b, y);

  gemm_qkv<<<dim3(3 * H / 256, M / 256, 1), 512, 0, stream>>>(
      y, wqkvT, qkv, H, H, H, 3 * H, 0, 0, 0);

  transpose_bf16<<<dim3(H / 32, N / 32, B), tb, 0, stream>>>(
      qkv + 2 * H, vT, 3 * H, N, (long long)N * 3 * H, (long long)H * N);

  for (int b0 = 0; b0 < B; b0 += g) {
    const bf16* qb = qkv + (size_t)b0 * N * 3 * H;
    gemm_qkt<<<dim3(N / 256, N / 256, g), 512, 0, stream>>>(
        qb, qb + H, S, H, 3 * H, 3 * H, N, (long long)N * 3 * H,
        (long long)N * 3 * H, (long long)N * N, 0.03125f);
    softmax_kernel<<<g * N, 256, 0, stream>>>(S, att);
    gemm_pv<<<dim3(H / 256, N / 256, g), 512, 0, stream>>>(
        att, vT + (size_t)b0 * H * N, out + (size_t)b0 * N * H, N, N, N, H,
        (long long)N * N, (long long)H * N, (long long)N * H,
        x + (size_t)b0 * N * H, (long long)N * H, H);
  }

  ln_kernel<<<M, 256, 0, stream>>>(out, ln2_g, ln2_b, y);

  gemm_ffn1<<<dim3(F / 256, M / 256, 1), 512, 0, stream>>>(
      y, w1T, h, H, H, H, F, b1);

  gemm_ffn2<<<dim3(H / 256, M / 256, 1), 512, 0, stream>>>(
      h, w2T, out, F, F, F, H, b2);
}

// Round 7
// 986.325 us; speedup vs baseline: 1.0395x; 1.0136x over previous
//
#include <hip/hip_runtime.h>
#include <hip/hip_bf16.h>

using bf16 = __hip_bfloat16;
typedef __bf16 bf16x8_t __attribute__((ext_vector_type(8)));
typedef float f32x4_t __attribute__((ext_vector_type(4)));

#define SBAR() __builtin_amdgcn_s_barrier()
#define WAITV4() asm volatile("s_waitcnt vmcnt(4)" ::: "memory")
#define WAITLG() asm volatile("s_waitcnt lgkmcnt(0)" ::: "memory")
#define PRIO1() __builtin_amdgcn_s_setprio(1)
#define PRIO0() __builtin_amdgcn_s_setprio(0)

__device__ __forceinline__ void gload_lds16(const bf16* g, const bf16* l) {
  __builtin_amdgcn_global_load_lds(
      (const __attribute__((address_space(1))) void*)g,
      (__attribute__((address_space(3))) void*)l, 16, 0, 0);
}

// exact-GELU via A&S 7.1.26 erf (|err| < 1.5e-7)
__device__ __forceinline__ float gelu_erf(float t) {
  const float ax = fabsf(t) * 0.70710678118654752f;
  const float u = 1.0f / fmaf(0.3275911f, ax, 1.0f);
  float p = fmaf(1.061405429f, u, -1.453152027f);
  p = fmaf(p, u, 1.421413741f);
  p = fmaf(p, u, -0.284496736f);
  p = fmaf(p, u, 0.254829592f);
  p = p * u * __expf(-ax * ax);
  float er = 1.0f - p;
  er = (t < 0.f) ? -er : er;
  return 0.5f * t * (1.0f + er);
}

// LDS: A = [buf][half][128 rows][64 k] at 0; B same at +32768 elem.
// ks-crossing swizzle: stored 16B-slot = logical_slot ^ (((row>>2)&1)<<2)
// -> each ds_read_b128 (fixed ks, 16 rows x 4 kgroups) covers all 32 banks.

// ---------------- NT GEMM: C[m][n] = sum_k A[m][k] * B[n][k] ----------------
// 256x256 tile, BK=64, 8 waves (2Mx4N), 4 quadrant-phases/K-tile,
// B-fragments register-resident across phases (24 ds_read/wave/K-tile).
template <int EPI>
__device__ __forceinline__ void gemm_body(
    const bf16* __restrict__ A, const bf16* __restrict__ B,
    void* __restrict__ Cv, int K, int lda, int ldb, int ldc,
    long long sA, long long sB, long long sC, float scale,
    const float* __restrict__ bias,
    const float* __restrict__ resid, long long sR, int ldr) {
  __shared__ __align__(16) bf16 smem[65536];  // 128 KiB
  const int tid = threadIdx.x;
  const int lane = tid & 63, wid = tid >> 6;
  const int wr = wid >> 2, wc = wid & 3;
  const int z = blockIdx.z;
  A += (size_t)z * sA;
  B += (size_t)z * sB;

  // T1: bijective XCD-aware block swizzle
  const int gx = gridDim.x, gy = gridDim.y;
  const int nwg = gx * gy;
  const int orig = blockIdx.x + gx * blockIdx.y;
  const int q = nwg >> 3, r = nwg & 7;
  const int xcd = orig & 7, loc = orig >> 3;
  const int wg = (xcd < r ? xcd * (q + 1) : r * (q + 1) + (xcd - r) * q) + loc;
  const int bm = (wg / gx) * 256;
  const int bn = (wg % gx) * 256;

  // ---- staging: thread -> (row srow & srow+64 of the half, swizzled slot)
  const int srow = tid >> 3;                              // 0..63
  const int sslot = (tid & 7) ^ (((srow >> 2) & 1) << 2);  // ks-crossing swz
  const bf16* gA = A + (size_t)(bm + srow) * lda + sslot * 8;
  const bf16* gB = B + (size_t)(bn + srow) * ldb + sslot * 8;
  const int sdst = wid * 512;  // wave-uniform LDS dest (HW adds lane*16B)

#define STAGE_A(SB, H, KE)                                                  \
  {                                                                         \
    const bf16* s_ = gA + (size_t)((H)*128) * lda + (KE);                   \
    gload_lds16(s_, smem + (SB)*16384 + (H)*8192 + sdst);                   \
    gload_lds16(s_ + (size_t)64 * lda,                                      \
                smem + (SB)*16384 + (H)*8192 + sdst + 4096);                \
  }
#define STAGE_B(SB, H, KE)                                                  \
  {                                                                         \
    const bf16* s_ = gB + (size_t)((H)*128) * ldb + (KE);                   \
    gload_lds16(s_, smem + 32768 + (SB)*16384 + (H)*8192 + sdst);           \
    gload_lds16(s_ + (size_t)64 * ldb,                                      \
                smem + 32768 + (SB)*16384 + (H)*8192 + sdst + 4096);        \
  }

  // ---- fragment read constants ----
  const int l15 = lane & 15, kg16 = lane >> 4;
  const int swz3 = ((l15 >> 2) & 1) << 2;  // row bit2 -> slot bit2 (ks bit)
  const int slotE0 = ((kg16 ^ swz3)) * 8;        // ks=0 stored slot (elems)
  const int slotE1 = ((4 + kg16) ^ swz3) * 8;    // ks=1
  const int rdA = wr * 4096 + l15 * 64;          // + mh*8192 + mf*1024
  const int rdB = 32768 + wc * 2048 + l15 * 64;  // + nh*8192 + nf*1024

  f32x4_t acc[8][4] = {};
  bf16x8_t avA[4][2], bv0[2][2], bv1[2][2];

#define LDA(BUF, MH)                                                        \
  _Pragma("unroll") for (int mf = 0; mf < 4; ++mf) {                        \
    avA[mf][0] = *(const bf16x8_t*)(smem + (BUF)*16384 + (MH)*8192 + rdA +  \
                                    mf * 1024 + slotE0);                    \
    avA[mf][1] = *(const bf16x8_t*)(smem + (BUF)*16384 + (MH)*8192 + rdA +  \
                                    mf * 1024 + slotE1);                    \
  }
#define LDB(BUF, NH, BV)                                                    \
  _Pragma("unroll") for (int nf = 0; nf < 2; ++nf) {                        \
    BV[nf][0] = *(const bf16x8_t*)(smem + (BUF)*16384 + (NH)*8192 + rdB +   \
                                   nf * 1024 + slotE0);                     \
    BV[nf][1] = *(const bf16x8_t*)(smem + (BUF)*16384 + (NH)*8192 + rdB +   \
                                   nf * 1024 + slotE1);                     \
  }
#define MMQ(MH, NH, BV)                                                     \
  PRIO1();                                                                  \
  _Pragma("unroll") for (int ks = 0; ks < 2; ++ks)                          \
      _Pragma("unroll") for (int mf = 0; mf < 4; ++mf)                      \
          _Pragma("unroll") for (int nf = 0; nf < 2; ++nf)                  \
              acc[(MH)*4 + mf][(NH)*2 + nf] =                               \
                  __builtin_amdgcn_mfma_f32_16x16x32_bf16(                  \
                      avA[mf][ks], BV[nf][ks],                              \
                      acc[(MH)*4 + mf][(NH)*2 + nf], 0, 0, 0);              \
  PRIO0();

// Quadrant snake (0,0)->(0,1)->(1,1)->(1,0); stage order A0,B0,B1,A1 of
// tile t+1 into buffer SB (one half-tile per phase, 2 loads). Uniform
// vmcnt(4) per phase-end: every first-read is 2 phases after its stage.
// ph4 reuses bv0 (B half 0) from registers -> no ds_read in ph4.
#define KTILE(BUF, SB, KE)                                                  \
  LDA(BUF, 0); LDB(BUF, 0, bv0); STAGE_A(SB, 0, KE);                        \
  SBAR(); WAITLG(); MMQ(0, 0, bv0); WAITV4(); SBAR();                      \
  LDB(BUF, 1, bv1); STAGE_B(SB, 0, KE);                                    \
  SBAR(); WAITLG(); MMQ(0, 1, bv1); WAITV4(); SBAR();                      \
  LDA(BUF, 1); STAGE_B(SB, 1, KE);                                         \
  SBAR(); WAITLG(); MMQ(1, 1, bv1); WAITV4(); SBAR();                      \
  STAGE_A(SB, 1, KE);                                                      \
  SBAR(); MMQ(1, 0, bv0); WAITV4(); SBAR();

  const int nt = K >> 6;  // 16/32/64 here (power of two)
  const int km = nt - 1;
  const int nit = nt >> 1;

  // prologue: tile0 halves in first-read order A0,B0,B1,A1; vmcnt(4)
  // -> A0,B0 resident; B1 proven at ph1-end, A1 at ph2-end.
  STAGE_A(0, 0, 0); STAGE_B(0, 0, 0); STAGE_B(0, 1, 0); STAGE_A(0, 1, 0);
  WAITV4();
  SBAR();

  for (int i = 0; i < nit; ++i) {
    const int keA = ((2 * i + 1) & km) * 64;
    const int keB = ((2 * i + 2) & km) * 64;  // wraps harmlessly on tail
    KTILE(0, 1, keA);
    KTILE(1, 0, keB);
  }
  asm volatile("s_waitcnt vmcnt(0) lgkmcnt(0)" ::: "memory");
  SBAR();

  // ---- epilogue (16x16 C/D: col=lane&15, row=(lane>>4)*4+reg) ----
#pragma unroll
  for (int mi = 0; mi < 8; ++mi) {
    const int rbase =
        bm + (mi >> 2) * 128 + wr * 64 + (mi & 3) * 16 + kg16 * 4;
#pragma unroll
    for (int ni = 0; ni < 4; ++ni) {
      const int cc = bn + (ni >> 1) * 128 + wc * 32 + (ni & 1) * 16 + l15;
#pragma unroll
      for (int jj = 0; jj < 4; ++jj) {
        const int rr = rbase + jj;
        const float v = acc[mi][ni][jj];
        if constexpr (EPI == 0) {
          ((bf16*)Cv)[(size_t)z * sC + (size_t)rr * ldc + cc] = __float2bfloat16(v);
        } else if constexpr (EPI == 1) {
          ((float*)Cv)[(size_t)z * sC + (size_t)rr * ldc + cc] = v * scale;
        } else if constexpr (EPI == 2) {
          ((float*)Cv)[(size_t)z * sC + (size_t)rr * ldc + cc] =
              v + resid[(size_t)z * sR + (size_t)rr * ldr + cc];
        } else if constexpr (EPI == 3) {
          ((bf16*)Cv)[(size_t)z * sC + (size_t)rr * ldc + cc] =
              __float2bfloat16(gelu_erf(v + bias[cc]));
        } else {
          float* Cf = (float*)Cv + (size_t)z * sC;
          const size_t idx = (size_t)rr * ldc + cc;
          Cf[idx] = Cf[idx] + v + bias[cc];
        }
      }
    }
  }
#undef STAGE_A
#undef STAGE_B
#undef LDA
#undef LDB
#undef MMQ
#undef KTILE
}

// Named wrappers (rocprof attribution)
__launch_bounds__(512, 1) __global__ void gemm_qkv(
    const bf16* A, const bf16* B, void* C, int K, int lda, int ldb, int ldc,
    long long sA, long long sB, long long sC) {
  gemm_body<0>(A, B, C, K, lda, ldb, ldc, sA, sB, sC, 1.f, nullptr, nullptr, 0, 0);
}
__launch_bounds__(512, 1) __global__ void gemm_qkt(
    const bf16* A, const bf16* B, void* C, int K, int lda, int ldb, int ldc,
    long long sA, long long sB, long long sC, float scale) {
  gemm_body<1>(A, B, C, K, lda, ldb, ldc, sA, sB, sC, scale, nullptr, nullptr, 0, 0);
}
__launch_bounds__(512, 1) __global__ void gemm_pv(
    const bf16* A, const bf16* B, void* C, int K, int lda, int ldb, int ldc,
    long long sA, long long sB, long long sC, const float* resid, long long sR,
    int ldr) {
  gemm_body<2>(A, B, C, K, lda, ldb, ldc, sA, sB, sC, 1.f, nullptr, resid, sR, ldr);
}
__launch_bounds__(512, 1) __global__ void gemm_ffn1(
    const bf16* A, const bf16* B, void* C, int K, int lda, int ldb, int ldc,
    const float* bias) {
  gemm_body<3>(A, B, C, K, lda, ldb, ldc, 0, 0, 0, 1.f, bias, nullptr, 0, 0);
}
__launch_bounds__(512, 1) __global__ void gemm_ffn2(
    const bf16* A, const bf16* B, void* C, int K, int lda, int ldb, int ldc,
    const float* bias) {
  gemm_body<4>(A, B, C, K, lda, ldb, ldc, 0, 0, 0, 1.f, bias, nullptr, 0, 0);
}

// ---------------- LayerNorm: fp32 in -> bf16 out, row length 1024 ----------
__global__ void ln_kernel(const float* __restrict__ X, const float* __restrict__ gw,
                          const float* __restrict__ bw, bf16* __restrict__ Y) {
  const int row = blockIdx.x, tid = threadIdx.x;
  const float4 xv = *(const float4*)(X + (size_t)row * 1024 + tid * 4);
  float s = xv.x + xv.y + xv.z + xv.w;
  float ss = xv.x * xv.x + xv.y * xv.y + xv.z * xv.z + xv.w * xv.w;
  __shared__ float red[8];
#pragma unroll
  for (int o = 32; o; o >>= 1) {
    s += __shfl_xor(s, o);
    ss += __shfl_xor(ss, o);
  }
  if ((tid & 63) == 0) {
    red[tid >> 6] = s;
    red[4 + (tid >> 6)] = ss;
  }
  __syncthreads();
  s = red[0] + red[1] + red[2] + red[3];
  ss = red[4] + red[5] + red[6] + red[7];
  const float mu = s * (1.f / 1024.f);
  const float var = ss * (1.f / 1024.f) - mu * mu;
  const float rs = rsqrtf(var + 1e-5f);
  const float4 gv = *(const float4*)(gw + tid * 4);
  const float4 bv = *(const float4*)(bw + tid * 4);
  union { ushort4 u; bf16 h[4]; } p;
  p.h[0] = __float2bfloat16((xv.x - mu) * rs * gv.x + bv.x);
  p.h[1] = __float2bfloat16((xv.y - mu) * rs * gv.y + bv.y);
  p.h[2] = __float2bfloat16((xv.z - mu) * rs * gv.z + bv.z);
  p.h[3] = __float2bfloat16((xv.w - mu) * rs * gv.w + bv.w);
  *(ushort4*)(Y + (size_t)row * 1024 + tid * 4) = p.u;
}

// ---------------- Softmax over rows of 2048 fp32 -> bf16 -------------------
__global__ void softmax_kernel(const float* __restrict__ S, bf16* __restrict__ P) {
  const size_t row = blockIdx.x;
  const int tid = threadIdx.x;
  const float4* sp = (const float4*)(S + row * 2048);
  const float4 v0 = sp[tid * 2], v1 = sp[tid * 2 + 1];
  float f[8] = {v0.x, v0.y, v0.z, v0.w, v1.x, v1.y, v1.z, v1.w};
  float m = f[0];
#pragma unroll
  for (int j = 1; j < 8; ++j) m = fmaxf(m, f[j]);
  __shared__ float red[4];
#pragma unroll
  for (int o = 32; o; o >>= 1) m = fmaxf(m, __shfl_xor(m, o));
  if ((tid & 63) == 0) red[tid >> 6] = m;
  __syncthreads();
  m = fmaxf(fmaxf(red[0], red[1]), fmaxf(red[2], red[3]));
  float s = 0.f;
#pragma unroll
  for (int j = 0; j < 8; ++j) {
    f[j] = expf(f[j] - m);
    s += f[j];
  }
#pragma unroll
  for (int o = 32; o; o >>= 1) s += __shfl_xor(s, o);
  __syncthreads();
  if ((tid & 63) == 0) red[tid >> 6] = s;
  __syncthreads();
  s = red[0] + red[1] + red[2] + red[3];
  const float inv = 1.f / s;
  union { uint4 u; bf16 h[8]; } p;
#pragma unroll
  for (int j = 0; j < 8; ++j) p.h[j] = __float2bfloat16(f[j] * inv);
  *(uint4*)(P + row * 2048 + tid * 8) = p.u;
}

// ------- Transpose + convert fp32 W[K][N] -> bf16 WT[rowoff+n][k] ----------
__global__ void transpose_conv(const float* __restrict__ W, bf16* __restrict__ WT,
                               int Nd, int ldT, int rowoff) {
  __shared__ float t[32][33];
  const int tx = threadIdx.x, ty = threadIdx.y;
  const int n0 = blockIdx.x * 32, k0 = blockIdx.y * 32;
#pragma unroll
  for (int j = 0; j < 4; ++j)
    t[ty + 8 * j][tx] = W[(size_t)(k0 + ty + 8 * j) * Nd + n0 + tx];
  __syncthreads();
#pragma unroll
  for (int j = 0; j < 4; ++j)
    WT[(size_t)(rowoff + n0 + ty + 8 * j) * ldT + k0 + tx] =
        __float2bfloat16(t[tx][ty + 8 * j]);
}

// ------- bf16 transpose: dst[c][r] = src[r][c], batched over z -------------
__global__ void transpose_bf16(const bf16* __restrict__ src, bf16* __restrict__ dst,
                               int ldsrc, int lddst, long long zs, long long zd) {
  __shared__ bf16 t[32][33];
  const int z = blockIdx.z;
  src += (size_t)z * zs;
  dst += (size_t)z * zd;
  const int tx = threadIdx.x, ty = threadIdx.y;
  const int c0 = blockIdx.x * 32, r0 = blockIdx.y * 32;
#pragma unroll
  for (int j = 0; j < 4; ++j)
    t[ty + 8 * j][tx] = src[(size_t)(r0 + ty + 8 * j) * ldsrc + c0 + tx];
  __syncthreads();
#pragma unroll
  for (int j = 0; j < 4; ++j)
    dst[(size_t)(c0 + ty + 8 * j) * lddst + r0 + tx] = t[tx][ty + 8 * j];
}

extern "C" void kernel_launch(void* const* d_in, const int* in_sizes, int n_in,
                              void* d_out, int out_size, void* d_ws, size_t ws_size,
                              hipStream_t stream) {
  const float* x = (const float*)d_in[0];
  const float* ln1_g = (const float*)d_in[1];
  const float* ln1_b = (const float*)d_in[2];
  const float* Wq = (const float*)d_in[3];
  const float* Wk = (const float*)d_in[4];
  const float* Wv = (const float*)d_in[5];
  const float* ln2_g = (const float*)d_in[6];
  const float* ln2_b = (const float*)d_in[7];
  const float* W1 = (const float*)d_in[8];
  const float* b1 = (const float*)d_in[9];
  const float* W2 = (const float*)d_in[10];
  const float* b2 = (const float*)d_in[11];
  float* out = (float*)d_out;

  constexpr int B = 8, N = 2048, H = 1024, F = 4096;
  constexpr int M = B * N;  // 16384

  const size_t WqkvTB = (size_t)3 * H * H * 2;
  const size_t W1TB = (size_t)H * F * 2;
  const size_t W2TB = (size_t)H * F * 2;
  const size_t yB = (size_t)M * H * 2;
  const size_t vTB = (size_t)M * H * 2;
  const size_t qkvB = (size_t)M * 3 * H * 2;
  const size_t SB1 = (size_t)N * N * 4;
  const size_t attB1 = (size_t)N * N * 2;
  const size_t hB = (size_t)M * F * 2;
  const size_t fixedB = WqkvTB + W1TB + W2TB + yB + vTB;

  int g = 8;
  for (; g > 1; g >>= 1) {
    size_t R = qkvB + (size_t)g * (SB1 + attB1);
    if (R < hB) R = hB;
    if (fixedB + R <= ws_size) break;
  }

  char* ws = (char*)d_ws;
  size_t o = 0;
  bf16* wqkvT = (bf16*)(ws + o); o += WqkvTB;
  bf16* w1T = (bf16*)(ws + o);   o += W1TB;
  bf16* w2T = (bf16*)(ws + o);   o += W2TB;
  bf16* y = (bf16*)(ws + o);     o += yB;
  bf16* vT = (bf16*)(ws + o);    o += vTB;
  char* Rb = ws + o;
  bf16* qkv = (bf16*)Rb;
  float* S = (float*)(Rb + qkvB);
  bf16* att = (bf16*)(Rb + qkvB + (size_t)g * SB1);
  bf16* h = (bf16*)Rb;

  const dim3 tb(32, 8);
  transpose_conv<<<dim3(H / 32, H / 32), tb, 0, stream>>>(Wq, wqkvT, H, H, 0);
  transpose_conv<<<dim3(H / 32, H / 32), tb, 0, stream>>>(Wk, wqkvT, H, H, H);
  transpose_conv<<<dim3(H / 32, H / 32), tb, 0, stream>>>(Wv, wqkvT, H, H, 2 * H);
  transpose_conv<<<dim3(F / 32, H / 32), tb, 0, stream>>>(W1, w1T, F, H, 0);
  transpose_conv<<<dim3(H / 32, F / 32), tb, 0, stream>>>(W2, w2T, H, F, 0);

  ln_kernel<<<M, 256, 0, stream>>>(x, ln1_g, ln1_b, y);

  gemm_qkv<<<dim3(3 * H / 256, M / 256, 1), 512, 0, stream>>>(
      y, wqkvT, qkv, H, H, H, 3 * H, 0, 0, 0);

  transpose_bf16<<<dim3(H / 32, N / 32, B), tb, 0, stream>>>(
      qkv + 2 * H, vT, 3 * H, N, (long long)N * 3 * H, (long long)H * N);

  for (int b0 = 0; b0 < B; b0 += g) {
    const bf16* qb = qkv + (size_t)b0 * N * 3 * H;
    gemm_qkt<<<dim3(N / 256, N / 256, g), 512, 0, stream>>>(
        qb, qb + H, S, H, 3 * H, 3 * H, N, (long long)N * 3 * H,
        (long long)N * 3 * H, (long long)N * N, 0.03125f);
    softmax_kernel<<<g * N, 256, 0, stream>>>(S, att);
    gemm_pv<<<dim3(H / 256, N / 256, g), 512, 0, stream>>>(
        att, vT + (size_t)b0 * H * N, out + (size_t)b0 * N * H, N, N, N, H,
        (long long)N * N, (long long)H * N, (long long)N * H,
        x + (size_t)b0 * N * H, (long long)N * H, H);
  }

  ln_kernel<<<M, 256, 0, stream>>>(out, ln2_g, ln2_b, y);

  gemm_ffn1<<<dim3(F / 256, M / 256, 1), 512, 0, stream>>>(
      y, w1T, h, H, H, H, F, b1);

  gemm_ffn2<<<dim3(H / 256, M / 256, 1), 512, 0, stream>>>(
      h, w2T, out, F, F, F, H, b2);
}

// Round 8
// 729.112 us; speedup vs baseline: 1.4063x; 1.3528x over previous
//
#include <hip/hip_runtime.h>
#include <hip/hip_bf16.h>

using bf16 = __hip_bfloat16;
typedef __bf16 bf16x8_t __attribute__((ext_vector_type(8)));
typedef float f32x4_t __attribute__((ext_vector_type(4)));

#define BM 128
#define BN 128
#define BK 64

__device__ __forceinline__ void gload_lds16(const void* g, void* l) {
  __builtin_amdgcn_global_load_lds(
      (__attribute__((address_space(1))) void*)g,
      (__attribute__((address_space(3))) void*)l, 16, 0, 0);
}

// exact-GELU via A&S 7.1.26 erf (|err| < 1.5e-7)
__device__ __forceinline__ float gelu_erf(float t) {
  const float ax = fabsf(t) * 0.70710678118654752f;
  const float u = 1.0f / fmaf(0.3275911f, ax, 1.0f);
  float p = fmaf(1.061405429f, u, -1.453152027f);
  p = fmaf(p, u, 1.421413741f);
  p = fmaf(p, u, -0.284496736f);
  p = fmaf(p, u, 0.254829592f);
  p = p * u * __expf(-ax * ax);
  float er = 1.0f - p;
  er = (t < 0.f) ? -er : er;
  return 0.5f * t * (1.0f + er);
}

// ---------------- NT GEMM: C[m][n] = sum_k A[m][k] * B[n][k] ----------------
// m97 structure: 128x128 tile, BK=64, 4 waves, single-buffer LDS (32 KiB),
// 2 barriers/K-step, multi-block occupancy for overlap. Slot-XOR swizzle:
// LDS physical (row, slot) holds global (row, slot ^ (row&7)) -> conflict-free
// ds_read_b128 (2 lanes/bank).
// EPI: 0 = bf16 out; 1 = bf16 out * scale; 2 = f32 out + resid;
//      3 = bf16 out gelu(acc+bias); 4 = f32 out += (in-place) acc + bias
template <int EPI>
__device__ __forceinline__ void gemm_body(
    const bf16* __restrict__ A, const bf16* __restrict__ B,
    void* __restrict__ Cv, int K, int lda, int ldb, int ldc,
    long long sA, long long sB, long long sC, float scale,
    const float* __restrict__ bias,
    const float* __restrict__ resid, long long sR, int ldr) {
  __shared__ __align__(16) bf16 As[BM * BK];
  __shared__ __align__(16) bf16 Bs[BN * BK];
  const int tid = threadIdx.x;
  const int lane = tid & 63, wid = tid >> 6;
  const int z = blockIdx.z;
  A += (size_t)z * sA;
  B += (size_t)z * sB;

  // T1: bijective XCD-aware block swizzle within the z-slice
  const int gx = gridDim.x, gy = gridDim.y;
  const int nwg = gx * gy;
  const int orig = blockIdx.x + gx * blockIdx.y;
  const int q = nwg >> 3, r = nwg & 7;
  const int xcd = orig & 7, loc = orig >> 3;
  const int wg = (xcd < r ? xcd * (q + 1) : r * (q + 1) + (xcd - r) * q) + loc;
  const int bm = (wg / gx) * BM;
  const int bn = (wg % gx) * BN;
  const int wr = wid >> 1, wc = wid & 1;

  // staging: 4 chunks/thread/operand; physical chunk ch = (row, slot),
  // global source slot = slot ^ (row&7); LDS dest linear.
  const bf16* ga[4];
  const bf16* gb[4];
  int lofs[4];
#pragma unroll
  for (int i = 0; i < 4; ++i) {
    int cb = i * 256 + wid * 64;  // wave-uniform chunk base
    int ch = cb + lane;
    int rr = ch >> 3, c = ch & 7;
    int cg = c ^ (rr & 7);        // pre-swizzled global slot
    ga[i] = A + (size_t)(bm + rr) * lda + cg * 8;
    gb[i] = B + (size_t)(bn + rr) * ldb + cg * 8;
    lofs[i] = cb * 8;
  }

  f32x4_t acc[4][4];
#pragma unroll
  for (int i = 0; i < 4; ++i)
#pragma unroll
    for (int j = 0; j < 4; ++j) acc[i][j] = (f32x4_t){0.f, 0.f, 0.f, 0.f};

  const int l15 = lane & 15, kg = lane >> 4;
  const int sw = l15 & 7;                 // (row&7) for every row this lane reads
  const int s0 = (kg ^ sw) * 8;           // kk=0 physical slot offset (elems)
  const int s1 = ((4 + kg) ^ sw) * 8;     // kk=1
  const int arow = wr * 64 + l15;
  const int brow = wc * 64 + l15;

  for (int kt = 0; kt < K; kt += BK) {
#pragma unroll
    for (int i = 0; i < 4; ++i) {
      gload_lds16(ga[i] + kt, As + lofs[i]);
      gload_lds16(gb[i] + kt, Bs + lofs[i]);
    }
    __syncthreads();
#pragma unroll
    for (int kk = 0; kk < 2; ++kk) {
      const int so = kk ? s1 : s0;
      bf16x8_t av[4], bv[4];
#pragma unroll
      for (int i = 0; i < 4; ++i)
        av[i] = *(const bf16x8_t*)(As + (arow + i * 16) * BK + so);
#pragma unroll
      for (int j = 0; j < 4; ++j)
        bv[j] = *(const bf16x8_t*)(Bs + (brow + j * 16) * BK + so);
#pragma unroll
      for (int i = 0; i < 4; ++i)
#pragma unroll
        for (int j = 0; j < 4; ++j)
          acc[i][j] = __builtin_amdgcn_mfma_f32_16x16x32_bf16(av[i], bv[j],
                                                              acc[i][j], 0, 0, 0);
    }
    __syncthreads();
  }

  // epilogue (16x16 C/D: col=lane&15, row=(lane>>4)*4+reg)
  const int row0 = bm + wr * 64 + kg * 4;
  const int col0 = bn + wc * 64 + l15;
#pragma unroll
  for (int i = 0; i < 4; ++i) {
#pragma unroll
    for (int j = 0; j < 4; ++j) {
#pragma unroll
      for (int jj = 0; jj < 4; ++jj) {
        const int rr = row0 + i * 16 + jj;
        const int cc = col0 + j * 16;
        const float v = acc[i][j][jj];
        if constexpr (EPI == 0) {
          ((bf16*)Cv)[(size_t)z * sC + (size_t)rr * ldc + cc] = __float2bfloat16(v);
        } else if constexpr (EPI == 1) {
          ((bf16*)Cv)[(size_t)z * sC + (size_t)rr * ldc + cc] =
              __float2bfloat16(v * scale);
        } else if constexpr (EPI == 2) {
          ((float*)Cv)[(size_t)z * sC + (size_t)rr * ldc + cc] =
              v + resid[(size_t)z * sR + (size_t)rr * ldr + cc];
        } else if constexpr (EPI == 3) {
          ((bf16*)Cv)[(size_t)z * sC + (size_t)rr * ldc + cc] =
              __float2bfloat16(gelu_erf(v + bias[cc]));
        } else {
          float* Cf = (float*)Cv + (size_t)z * sC;
          const size_t idx = (size_t)rr * ldc + cc;
          Cf[idx] = Cf[idx] + v + bias[cc];
        }
      }
    }
  }
}

// Named wrappers (rocprof attribution)
__global__ void gemm_qkv(const bf16* A, const bf16* B, void* C, int K, int lda,
                         int ldb, int ldc, long long sA, long long sB,
                         long long sC) {
  gemm_body<0>(A, B, C, K, lda, ldb, ldc, sA, sB, sC, 1.f, nullptr, nullptr, 0, 0);
}
__global__ void gemm_qkt(const bf16* A, const bf16* B, void* C, int K, int lda,
                         int ldb, int ldc, long long sA, long long sB,
                         long long sC, float scale) {
  gemm_body<1>(A, B, C, K, lda, ldb, ldc, sA, sB, sC, scale, nullptr, nullptr, 0, 0);
}
__global__ void gemm_pv(const bf16* A, const bf16* B, void* C, int K, int lda,
                        int ldb, int ldc, long long sA, long long sB,
                        long long sC, const float* resid, long long sR, int ldr) {
  gemm_body<2>(A, B, C, K, lda, ldb, ldc, sA, sB, sC, 1.f, nullptr, resid, sR, ldr);
}
__global__ void gemm_ffn1(const bf16* A, const bf16* B, void* C, int K, int lda,
                          int ldb, int ldc, const float* bias) {
  gemm_body<3>(A, B, C, K, lda, ldb, ldc, 0, 0, 0, 1.f, bias, nullptr, 0, 0);
}
__global__ void gemm_ffn2(const bf16* A, const bf16* B, void* C, int K, int lda,
                          int ldb, int ldc, const float* bias) {
  gemm_body<4>(A, B, C, K, lda, ldb, ldc, 0, 0, 0, 1.f, bias, nullptr, 0, 0);
}

// ---------------- LayerNorm: fp32 in -> bf16 out, row length 1024 ----------
__global__ void ln_kernel(const float* __restrict__ X, const float* __restrict__ gw,
                          const float* __restrict__ bw, bf16* __restrict__ Y) {
  const int row = blockIdx.x, tid = threadIdx.x;
  const float4 xv = *(const float4*)(X + (size_t)row * 1024 + tid * 4);
  float s = xv.x + xv.y + xv.z + xv.w;
  float ss = xv.x * xv.x + xv.y * xv.y + xv.z * xv.z + xv.w * xv.w;
  __shared__ float red[8];
#pragma unroll
  for (int o = 32; o; o >>= 1) {
    s += __shfl_xor(s, o);
    ss += __shfl_xor(ss, o);
  }
  if ((tid & 63) == 0) {
    red[tid >> 6] = s;
    red[4 + (tid >> 6)] = ss;
  }
  __syncthreads();
  s = red[0] + red[1] + red[2] + red[3];
  ss = red[4] + red[5] + red[6] + red[7];
  const float mu = s * (1.f / 1024.f);
  const float var = ss * (1.f / 1024.f) - mu * mu;
  const float rs = rsqrtf(var + 1e-5f);
  const float4 gv = *(const float4*)(gw + tid * 4);
  const float4 bv = *(const float4*)(bw + tid * 4);
  union { ushort4 u; bf16 h[4]; } p;
  p.h[0] = __float2bfloat16((xv.x - mu) * rs * gv.x + bv.x);
  p.h[1] = __float2bfloat16((xv.y - mu) * rs * gv.y + bv.y);
  p.h[2] = __float2bfloat16((xv.z - mu) * rs * gv.z + bv.z);
  p.h[3] = __float2bfloat16((xv.w - mu) * rs * gv.w + bv.w);
  *(ushort4*)(Y + (size_t)row * 1024 + tid * 4) = p.u;
}

// ---------------- Softmax over rows of 2048 bf16 -> bf16 -------------------
__global__ void softmax_kernel(const bf16* __restrict__ S, bf16* __restrict__ P) {
  const size_t row = blockIdx.x;
  const int tid = threadIdx.x;
  union { uint4 u; unsigned short s[8]; } in;
  in.u = *(const uint4*)(S + row * 2048 + tid * 8);
  float f[8];
#pragma unroll
  for (int j = 0; j < 8; ++j)
    f[j] = __uint_as_float((unsigned)in.s[j] << 16);
  float m = f[0];
#pragma unroll
  for (int j = 1; j < 8; ++j) m = fmaxf(m, f[j]);
  __shared__ float red[4];
#pragma unroll
  for (int o = 32; o; o >>= 1) m = fmaxf(m, __shfl_xor(m, o));
  if ((tid & 63) == 0) red[tid >> 6] = m;
  __syncthreads();
  m = fmaxf(fmaxf(red[0], red[1]), fmaxf(red[2], red[3]));
  float s = 0.f;
#pragma unroll
  for (int j = 0; j < 8; ++j) {
    f[j] = __expf(f[j] - m);
    s += f[j];
  }
#pragma unroll
  for (int o = 32; o; o >>= 1) s += __shfl_xor(s, o);
  __syncthreads();
  if ((tid & 63) == 0) red[tid >> 6] = s;
  __syncthreads();
  s = red[0] + red[1] + red[2] + red[3];
  const float inv = 1.f / s;
  union { uint4 u; bf16 h[8]; } p;
#pragma unroll
  for (int j = 0; j < 8; ++j) p.h[j] = __float2bfloat16(f[j] * inv);
  *(uint4*)(P + row * 2048 + tid * 8) = p.u;
}

// ------- Transpose + convert fp32 W[K][N] -> bf16 WT[rowoff+n][k] ----------
__global__ void transpose_conv(const float* __restrict__ W, bf16* __restrict__ WT,
                               int Nd, int ldT, int rowoff) {
  __shared__ float t[32][33];
  const int tx = threadIdx.x, ty = threadIdx.y;
  const int n0 = blockIdx.x * 32, k0 = blockIdx.y * 32;
#pragma unroll
  for (int j = 0; j < 4; ++j)
    t[ty + 8 * j][tx] = W[(size_t)(k0 + ty + 8 * j) * Nd + n0 + tx];
  __syncthreads();
#pragma unroll
  for (int j = 0; j < 4; ++j)
    WT[(size_t)(rowoff + n0 + ty + 8 * j) * ldT + k0 + tx] =
        __float2bfloat16(t[tx][ty + 8 * j]);
}

// ------- bf16 transpose: dst[c][r] = src[r][c], batched over z -------------
__global__ void transpose_bf16(const bf16* __restrict__ src, bf16* __restrict__ dst,
                               int ldsrc, int lddst, long long zs, long long zd) {
  __shared__ bf16 t[32][33];
  const int z = blockIdx.z;
  src += (size_t)z * zs;
  dst += (size_t)z * zd;
  const int tx = threadIdx.x, ty = threadIdx.y;
  const int c0 = blockIdx.x * 32, r0 = blockIdx.y * 32;
#pragma unroll
  for (int j = 0; j < 4; ++j)
    t[ty + 8 * j][tx] = src[(size_t)(r0 + ty + 8 * j) * ldsrc + c0 + tx];
  __syncthreads();
#pragma unroll
  for (int j = 0; j < 4; ++j)
    dst[(size_t)(c0 + ty + 8 * j) * lddst + r0 + tx] = t[tx][ty + 8 * j];
}

extern "C" void kernel_launch(void* const* d_in, const int* in_sizes, int n_in,
                              void* d_out, int out_size, void* d_ws, size_t ws_size,
                              hipStream_t stream) {
  const float* x = (const float*)d_in[0];
  const float* ln1_g = (const float*)d_in[1];
  const float* ln1_b = (const float*)d_in[2];
  const float* Wq = (const float*)d_in[3];
  const float* Wk = (const float*)d_in[4];
  const float* Wv = (const float*)d_in[5];
  const float* ln2_g = (const float*)d_in[6];
  const float* ln2_b = (const float*)d_in[7];
  const float* W1 = (const float*)d_in[8];
  const float* b1 = (const float*)d_in[9];
  const float* W2 = (const float*)d_in[10];
  const float* b2 = (const float*)d_in[11];
  float* out = (float*)d_out;

  constexpr int B = 8, N = 2048, H = 1024, F = 4096;
  constexpr int M = B * N;  // 16384

  const size_t WqkvTB = (size_t)3 * H * H * 2;
  const size_t W1TB = (size_t)H * F * 2;
  const size_t W2TB = (size_t)H * F * 2;
  const size_t yB = (size_t)M * H * 2;
  const size_t vTB = (size_t)M * H * 2;
  const size_t qkvB = (size_t)M * 3 * H * 2;
  const size_t SB1 = (size_t)N * N * 2;   // bf16 scores now
  const size_t attB1 = (size_t)N * N * 2;
  const size_t hB = (size_t)M * F * 2;
  const size_t fixedB = WqkvTB + W1TB + W2TB + yB + vTB;

  int g = 8;
  for (; g > 1; g >>= 1) {
    size_t R = qkvB + (size_t)g * (SB1 + attB1);
    if (R < hB) R = hB;
    if (fixedB + R <= ws_size) break;
  }

  char* ws = (char*)d_ws;
  size_t o = 0;
  bf16* wqkvT = (bf16*)(ws + o); o += WqkvTB;
  bf16* w1T = (bf16*)(ws + o);   o += W1TB;
  bf16* w2T = (bf16*)(ws + o);   o += W2TB;
  bf16* y = (bf16*)(ws + o);     o += yB;
  bf16* vT = (bf16*)(ws + o);    o += vTB;
  char* Rb = ws + o;
  bf16* qkv = (bf16*)Rb;
  bf16* S = (bf16*)(Rb + qkvB);
  bf16* att = (bf16*)(Rb + qkvB + (size_t)g * SB1);
  bf16* h = (bf16*)Rb;  // overlays qkv/S/att after attention is done

  const dim3 tb(32, 8);
  transpose_conv<<<dim3(H / 32, H / 32), tb, 0, stream>>>(Wq, wqkvT, H, H, 0);
  transpose_conv<<<dim3(H / 32, H / 32), tb, 0, stream>>>(Wk, wqkvT, H, H, H);
  transpose_conv<<<dim3(H / 32, H / 32), tb, 0, stream>>>(Wv, wqkvT, H, H, 2 * H);
  transpose_conv<<<dim3(F / 32, H / 32), tb, 0, stream>>>(W1, w1T, F, H, 0);
  transpose_conv<<<dim3(H / 32, F / 32), tb, 0, stream>>>(W2, w2T, H, F, 0);

  ln_kernel<<<M, 256, 0, stream>>>(x, ln1_g, ln1_b, y);

  gemm_qkv<<<dim3(3 * H / BN, M / BM, 1), 256, 0, stream>>>(
      y, wqkvT, qkv, H, H, H, 3 * H, 0, 0, 0);

  transpose_bf16<<<dim3(H / 32, N / 32, B), tb, 0, stream>>>(
      qkv + 2 * H, vT, 3 * H, N, (long long)N * 3 * H, (long long)H * N);

  for (int b0 = 0; b0 < B; b0 += g) {
    const bf16* qb = qkv + (size_t)b0 * N * 3 * H;
    gemm_qkt<<<dim3(N / BN, N / BM, g), 256, 0, stream>>>(
        qb, qb + H, S, H, 3 * H, 3 * H, N, (long long)N * 3 * H,
        (long long)N * 3 * H, (long long)N * N, 0.03125f);
    softmax_kernel<<<g * N, 256, 0, stream>>>(S, att);
    gemm_pv<<<dim3(H / BN, N / BM, g), 256, 0, stream>>>(
        att, vT + (size_t)b0 * H * N, out + (size_t)b0 * N * H, N, N, N, H,
        (long long)N * N, (long long)H * N, (long long)N * H,
        x + (size_t)b0 * N * H, (long long)N * H, H);
  }

  ln_kernel<<<M, 256, 0, stream>>>(out, ln2_g, ln2_b, y);

  gemm_ffn1<<<dim3(F / BN, M / BM, 1), 256, 0, stream>>>(
      y, w1T, h, H, H, H, F, b1);

  gemm_ffn2<<<dim3(H / BN, M / BM, 1), 256, 0, stream>>>(
      h, w2T, out, F, F, F, H, b2);
}

// Round 9
// 717.803 us; speedup vs baseline: 1.4284x; 1.0158x over previous
//
#include <hip/hip_runtime.h>
#include <hip/hip_bf16.h>

using bf16 = __hip_bfloat16;
typedef __bf16 bf16x8_t __attribute__((ext_vector_type(8)));
typedef float f32x4_t __attribute__((ext_vector_type(4)));

#define BM 128
#define BN 128
#define BK 64

__device__ __forceinline__ void gload_lds16(const void* g, void* l) {
  __builtin_amdgcn_global_load_lds(
      (__attribute__((address_space(1))) void*)g,
      (__attribute__((address_space(3))) void*)l, 16, 0, 0);
}

// GELU via A&S 7.1.25 3-term erf (|err| < 2.5e-5; bf16 output => invisible)
__device__ __forceinline__ float gelu_erf(float t) {
  const float xs = fabsf(t) * 0.70710678118654752f;
  const float u = 1.0f / fmaf(0.47047f, xs, 1.0f);
  float p = fmaf(0.7478556f, u, -0.0958798f);
  p = fmaf(p, u, 0.3480242f);
  const float er = 1.0f - p * u * __expf(-xs * xs);
  const float ers = (t < 0.f) ? -er : er;
  return 0.5f * t * (1.0f + ers);
}

// ---------------- NT GEMM: C[m][n] = sum_k A[m][k] * B[n][k] ----------------
// m97 structure: 128x128 tile, BK=64, 4 waves, single-buffer LDS (32 KiB),
// 2 barriers/K-step, multi-block occupancy for overlap. Slot-XOR swizzle:
// LDS physical (row, slot) holds global (row, slot ^ (row&7)) -> conflict-free
// ds_read_b128. Block order: XCD-bijective outer, then GROUP_M=8 bm-fast
// super-tiles (B-panel reused 8x back-to-back in L2; A-group <= 2 MB hot).
// EPI: 0 = bf16 out; 1 = bf16 out * scale; 2 = f32 out + resid;
//      3 = bf16 out gelu(acc+bias); 4 = f32 out += (in-place) acc + bias
template <int EPI>
__device__ __forceinline__ void gemm_body(
    const bf16* __restrict__ A, const bf16* __restrict__ B,
    void* __restrict__ Cv, int K, int lda, int ldb, int ldc,
    long long sA, long long sB, long long sC, float scale,
    const float* __restrict__ bias,
    const float* __restrict__ resid, long long sR, int ldr) {
  __shared__ __align__(16) bf16 As[BM * BK];
  __shared__ __align__(16) bf16 Bs[BN * BK];
  const int tid = threadIdx.x;
  const int lane = tid & 63, wid = tid >> 6;
  const int z = blockIdx.z;
  A += (size_t)z * sA;
  B += (size_t)z * sB;

  // T1: bijective XCD-aware block swizzle within the z-slice
  const int gx = gridDim.x, gy = gridDim.y;
  const int nwg = gx * gy;
  const int orig = blockIdx.x + gx * blockIdx.y;
  const int q = nwg >> 3, r = nwg & 7;
  const int xcd = orig & 7, loc = orig >> 3;
  const int wg = (xcd < r ? xcd * (q + 1) : r * (q + 1) + (xcd - r) * q) + loc;
  // GROUP_M=8 super-tile: bm-fast within 8-row groups (gy % 8 == 0 here)
  const int m_in = wg & 7;
  const int rest = wg >> 3;
  const int bn = (rest % gx) * BN;
  const int bm = ((rest / gx) * 8 + m_in) * BM;
  const int wr = wid >> 1, wc = wid & 1;

  // staging: 4 chunks/thread/operand; physical chunk ch = (row, slot),
  // global source slot = slot ^ (row&7); LDS dest linear.
  const bf16* ga[4];
  const bf16* gb[4];
  int lofs[4];
#pragma unroll
  for (int i = 0; i < 4; ++i) {
    int cb = i * 256 + wid * 64;  // wave-uniform chunk base
    int ch = cb + lane;
    int rr = ch >> 3, c = ch & 7;
    int cg = c ^ (rr & 7);        // pre-swizzled global slot
    ga[i] = A + (size_t)(bm + rr) * lda + cg * 8;
    gb[i] = B + (size_t)(bn + rr) * ldb + cg * 8;
    lofs[i] = cb * 8;
  }

  f32x4_t acc[4][4];
#pragma unroll
  for (int i = 0; i < 4; ++i)
#pragma unroll
    for (int j = 0; j < 4; ++j) acc[i][j] = (f32x4_t){0.f, 0.f, 0.f, 0.f};

  const int l15 = lane & 15, kg = lane >> 4;
  const int sw = l15 & 7;                 // (row&7) for every row this lane reads
  const int s0 = (kg ^ sw) * 8;           // kk=0 physical slot offset (elems)
  const int s1 = ((4 + kg) ^ sw) * 8;     // kk=1
  const int arow = wr * 64 + l15;
  const int brow = wc * 64 + l15;

  for (int kt = 0; kt < K; kt += BK) {
#pragma unroll
    for (int i = 0; i < 4; ++i) {
      gload_lds16(ga[i] + kt, As + lofs[i]);
      gload_lds16(gb[i] + kt, Bs + lofs[i]);
    }
    __syncthreads();
#pragma unroll
    for (int kk = 0; kk < 2; ++kk) {
      const int so = kk ? s1 : s0;
      bf16x8_t av[4], bv[4];
#pragma unroll
      for (int i = 0; i < 4; ++i)
        av[i] = *(const bf16x8_t*)(As + (arow + i * 16) * BK + so);
#pragma unroll
      for (int j = 0; j < 4; ++j)
        bv[j] = *(const bf16x8_t*)(Bs + (brow + j * 16) * BK + so);
#pragma unroll
      for (int i = 0; i < 4; ++i)
#pragma unroll
        for (int j = 0; j < 4; ++j)
          acc[i][j] = __builtin_amdgcn_mfma_f32_16x16x32_bf16(av[i], bv[j],
                                                              acc[i][j], 0, 0, 0);
    }
    __syncthreads();
  }

  // epilogue (16x16 C/D: col=lane&15, row=(lane>>4)*4+reg)
  const int row0 = bm + wr * 64 + kg * 4;
  const int col0 = bn + wc * 64 + l15;
#pragma unroll
  for (int i = 0; i < 4; ++i) {
#pragma unroll
    for (int j = 0; j < 4; ++j) {
#pragma unroll
      for (int jj = 0; jj < 4; ++jj) {
        const int rr = row0 + i * 16 + jj;
        const int cc = col0 + j * 16;
        const float v = acc[i][j][jj];
        if constexpr (EPI == 0) {
          ((bf16*)Cv)[(size_t)z * sC + (size_t)rr * ldc + cc] = __float2bfloat16(v);
        } else if constexpr (EPI == 1) {
          ((bf16*)Cv)[(size_t)z * sC + (size_t)rr * ldc + cc] =
              __float2bfloat16(v * scale);
        } else if constexpr (EPI == 2) {
          ((float*)Cv)[(size_t)z * sC + (size_t)rr * ldc + cc] =
              v + resid[(size_t)z * sR + (size_t)rr * ldr + cc];
        } else if constexpr (EPI == 3) {
          ((bf16*)Cv)[(size_t)z * sC + (size_t)rr * ldc + cc] =
              __float2bfloat16(gelu_erf(v + bias[cc]));
        } else {
          float* Cf = (float*)Cv + (size_t)z * sC;
          const size_t idx = (size_t)rr * ldc + cc;
          Cf[idx] = Cf[idx] + v + bias[cc];
        }
      }
    }
  }
}

// Named wrappers (rocprof attribution)
__global__ void gemm_qkv(const bf16* A, const bf16* B, void* C, int K, int lda,
                         int ldb, int ldc, long long sA, long long sB,
                         long long sC) {
  gemm_body<0>(A, B, C, K, lda, ldb, ldc, sA, sB, sC, 1.f, nullptr, nullptr, 0, 0);
}
__global__ void gemm_qkt(const bf16* A, const bf16* B, void* C, int K, int lda,
                         int ldb, int ldc, long long sA, long long sB,
                         long long sC, float scale) {
  gemm_body<1>(A, B, C, K, lda, ldb, ldc, sA, sB, sC, scale, nullptr, nullptr, 0, 0);
}
__global__ void gemm_pv(const bf16* A, const bf16* B, void* C, int K, int lda,
                        int ldb, int ldc, long long sA, long long sB,
                        long long sC, const float* resid, long long sR, int ldr) {
  gemm_body<2>(A, B, C, K, lda, ldb, ldc, sA, sB, sC, 1.f, nullptr, resid, sR, ldr);
}
__global__ void gemm_ffn1(const bf16* A, const bf16* B, void* C, int K, int lda,
                          int ldb, int ldc, const float* bias) {
  gemm_body<3>(A, B, C, K, lda, ldb, ldc, 0, 0, 0, 1.f, bias, nullptr, 0, 0);
}
__global__ void gemm_ffn2(const bf16* A, const bf16* B, void* C, int K, int lda,
                          int ldb, int ldc, const float* bias) {
  gemm_body<4>(A, B, C, K, lda, ldb, ldc, 0, 0, 0, 1.f, bias, nullptr, 0, 0);
}

// ---------------- LayerNorm: fp32 in -> bf16 out, row length 1024 ----------
__global__ void ln_kernel(const float* __restrict__ X, const float* __restrict__ gw,
                          const float* __restrict__ bw, bf16* __restrict__ Y) {
  const int row = blockIdx.x, tid = threadIdx.x;
  const float4 xv = *(const float4*)(X + (size_t)row * 1024 + tid * 4);
  float s = xv.x + xv.y + xv.z + xv.w;
  float ss = xv.x * xv.x + xv.y * xv.y + xv.z * xv.z + xv.w * xv.w;
  __shared__ float red[8];
#pragma unroll
  for (int o = 32; o; o >>= 1) {
    s += __shfl_xor(s, o);
    ss += __shfl_xor(ss, o);
  }
  if ((tid & 63) == 0) {
    red[tid >> 6] = s;
    red[4 + (tid >> 6)] = ss;
  }
  __syncthreads();
  s = red[0] + red[1] + red[2] + red[3];
  ss = red[4] + red[5] + red[6] + red[7];
  const float mu = s * (1.f / 1024.f);
  const float var = ss * (1.f / 1024.f) - mu * mu;
  const float rs = rsqrtf(var + 1e-5f);
  const float4 gv = *(const float4*)(gw + tid * 4);
  const float4 bv = *(const float4*)(bw + tid * 4);
  union { ushort4 u; bf16 h[4]; } p;
  p.h[0] = __float2bfloat16((xv.x - mu) * rs * gv.x + bv.x);
  p.h[1] = __float2bfloat16((xv.y - mu) * rs * gv.y + bv.y);
  p.h[2] = __float2bfloat16((xv.z - mu) * rs * gv.z + bv.z);
  p.h[3] = __float2bfloat16((xv.w - mu) * rs * gv.w + bv.w);
  *(ushort4*)(Y + (size_t)row * 1024 + tid * 4) = p.u;
}

// ---------------- Softmax over rows of 2048 bf16 -> bf16 -------------------
__global__ void softmax_kernel(const bf16* __restrict__ S, bf16* __restrict__ P) {
  const size_t row = blockIdx.x;
  const int tid = threadIdx.x;
  union { uint4 u; unsigned short s[8]; } in;
  in.u = *(const uint4*)(S + row * 2048 + tid * 8);
  float f[8];
#pragma unroll
  for (int j = 0; j < 8; ++j)
    f[j] = __uint_as_float((unsigned)in.s[j] << 16);
  float m = f[0];
#pragma unroll
  for (int j = 1; j < 8; ++j) m = fmaxf(m, f[j]);
  __shared__ float red[4];
#pragma unroll
  for (int o = 32; o; o >>= 1) m = fmaxf(m, __shfl_xor(m, o));
  if ((tid & 63) == 0) red[tid >> 6] = m;
  __syncthreads();
  m = fmaxf(fmaxf(red[0], red[1]), fmaxf(red[2], red[3]));
  float s = 0.f;
#pragma unroll
  for (int j = 0; j < 8; ++j) {
    f[j] = __expf(f[j] - m);
    s += f[j];
  }
#pragma unroll
  for (int o = 32; o; o >>= 1) s += __shfl_xor(s, o);
  __syncthreads();
  if ((tid & 63) == 0) red[tid >> 6] = s;
  __syncthreads();
  s = red[0] + red[1] + red[2] + red[3];
  const float inv = 1.f / s;
  union { uint4 u; bf16 h[8]; } p;
#pragma unroll
  for (int j = 0; j < 8; ++j) p.h[j] = __float2bfloat16(f[j] * inv);
  *(uint4*)(P + row * 2048 + tid * 8) = p.u;
}

// ------- Transpose + convert fp32 W[K][N] -> bf16 WT[rowoff+n][k] ----------
__global__ void transpose_conv(const float* __restrict__ W, bf16* __restrict__ WT,
                               int Nd, int ldT, int rowoff) {
  __shared__ float t[32][33];
  const int tx = threadIdx.x, ty = threadIdx.y;
  const int n0 = blockIdx.x * 32, k0 = blockIdx.y * 32;
#pragma unroll
  for (int j = 0; j < 4; ++j)
    t[ty + 8 * j][tx] = W[(size_t)(k0 + ty + 8 * j) * Nd + n0 + tx];
  __syncthreads();
#pragma unroll
  for (int j = 0; j < 4; ++j)
    WT[(size_t)(rowoff + n0 + ty + 8 * j) * ldT + k0 + tx] =
        __float2bfloat16(t[tx][ty + 8 * j]);
}

// ------- bf16 transpose: dst[c][r] = src[r][c], batched over z -------------
__global__ void transpose_bf16(const bf16* __restrict__ src, bf16* __restrict__ dst,
                               int ldsrc, int lddst, long long zs, long long zd) {
  __shared__ bf16 t[32][33];
  const int z = blockIdx.z;
  src += (size_t)z * zs;
  dst += (size_t)z * zd;
  const int tx = threadIdx.x, ty = threadIdx.y;
  const int c0 = blockIdx.x * 32, r0 = blockIdx.y * 32;
#pragma unroll
  for (int j = 0; j < 4; ++j)
    t[ty + 8 * j][tx] = src[(size_t)(r0 + ty + 8 * j) * ldsrc + c0 + tx];
  __syncthreads();
#pragma unroll
  for (int j = 0; j < 4; ++j)
    dst[(size_t)(c0 + ty + 8 * j) * lddst + r0 + tx] = t[tx][ty + 8 * j];
}

extern "C" void kernel_launch(void* const* d_in, const int* in_sizes, int n_in,
                              void* d_out, int out_size, void* d_ws, size_t ws_size,
                              hipStream_t stream) {
  const float* x = (const float*)d_in[0];
  const float* ln1_g = (const float*)d_in[1];
  const float* ln1_b = (const float*)d_in[2];
  const float* Wq = (const float*)d_in[3];
  const float* Wk = (const float*)d_in[4];
  const float* Wv = (const float*)d_in[5];
  const float* ln2_g = (const float*)d_in[6];
  const float* ln2_b = (const float*)d_in[7];
  const float* W1 = (const float*)d_in[8];
  const float* b1 = (const float*)d_in[9];
  const float* W2 = (const float*)d_in[10];
  const float* b2 = (const float*)d_in[11];
  float* out = (float*)d_out;

  constexpr int B = 8, N = 2048, H = 1024, F = 4096;
  constexpr int M = B * N;  // 16384

  const size_t WqkvTB = (size_t)3 * H * H * 2;
  const size_t W1TB = (size_t)H * F * 2;
  const size_t W2TB = (size_t)H * F * 2;
  const size_t yB = (size_t)M * H * 2;
  const size_t vTB = (size_t)M * H * 2;
  const size_t qkvB = (size_t)M * 3 * H * 2;
  const size_t SB1 = (size_t)N * N * 2;   // bf16 scores
  const size_t attB1 = (size_t)N * N * 2;
  const size_t hB = (size_t)M * F * 2;
  const size_t fixedB = WqkvTB + W1TB + W2TB + yB + vTB;

  int g = 8;
  for (; g > 1; g >>= 1) {
    size_t R = qkvB + (size_t)g * (SB1 + attB1);
    if (R < hB) R = hB;
    if (fixedB + R <= ws_size) break;
  }

  char* ws = (char*)d_ws;
  size_t o = 0;
  bf16* wqkvT = (bf16*)(ws + o); o += WqkvTB;
  bf16* w1T = (bf16*)(ws + o);   o += W1TB;
  bf16* w2T = (bf16*)(ws + o);   o += W2TB;
  bf16* y = (bf16*)(ws + o);     o += yB;
  bf16* vT = (bf16*)(ws + o);    o += vTB;
  char* Rb = ws + o;
  bf16* qkv = (bf16*)Rb;
  bf16* S = (bf16*)(Rb + qkvB);
  bf16* att = (bf16*)(Rb + qkvB + (size_t)g * SB1);
  bf16* h = (bf16*)Rb;  // overlays qkv/S/att after attention is done

  const dim3 tb(32, 8);
  transpose_conv<<<dim3(H / 32, H / 32), tb, 0, stream>>>(Wq, wqkvT, H, H, 0);
  transpose_conv<<<dim3(H / 32, H / 32), tb, 0, stream>>>(Wk, wqkvT, H, H, H);
  transpose_conv<<<dim3(H / 32, H / 32), tb, 0, stream>>>(Wv, wqkvT, H, H, 2 * H);
  transpose_conv<<<dim3(F / 32, H / 32), tb, 0, stream>>>(W1, w1T, F, H, 0);
  transpose_conv<<<dim3(H / 32, F / 32), tb, 0, stream>>>(W2, w2T, H, F, 0);

  ln_kernel<<<M, 256, 0, stream>>>(x, ln1_g, ln1_b, y);

  gemm_qkv<<<dim3(3 * H / BN, M / BM, 1), 256, 0, stream>>>(
      y, wqkvT, qkv, H, H, H, 3 * H, 0, 0, 0);

  transpose_bf16<<<dim3(H / 32, N / 32, B), tb, 0, stream>>>(
      qkv + 2 * H, vT, 3 * H, N, (long long)N * 3 * H, (long long)H * N);

  for (int b0 = 0; b0 < B; b0 += g) {
    const bf16* qb = qkv + (size_t)b0 * N * 3 * H;
    gemm_qkt<<<dim3(N / BN, N / BM, g), 256, 0, stream>>>(
        qb, qb + H, S, H, 3 * H, 3 * H, N, (long long)N * 3 * H,
        (long long)N * 3 * H, (long long)N * N, 0.03125f);
    softmax_kernel<<<g * N, 256, 0, stream>>>(S, att);
    gemm_pv<<<dim3(H / BN, N / BM, g), 256, 0, stream>>>(
        att, vT + (size_t)b0 * H * N, out + (size_t)b0 * N * H, N, N, N, H,
        (long long)N * N, (long long)H * N, (long long)N * H,
        x + (size_t)b0 * N * H, (long long)N * H, H);
  }

  ln_kernel<<<M, 256, 0, stream>>>(out, ln2_g, ln2_b, y);

  gemm_ffn1<<<dim3(F / BN, M / BM, 1), 256, 0, stream>>>(
      y, w1T, h, H, H, H, F, b1);

  gemm_ffn2<<<dim3(H / BN, M / BM, 1), 256, 0, stream>>>(
      h, w2T, out, F, F, F, H, b2);
}